// Round 5
// baseline (948.431 us; speedup 1.0000x reference)
//
#include <hip/hip_runtime.h>
#include <math.h>

#define IMH 192
#define IMW 192
#define HWF 36864
#define PDIM 194

typedef unsigned short u16t;
typedef __attribute__((ext_vector_type(8))) short short8;
typedef __attribute__((ext_vector_type(4))) float f32x4;

__device__ __forceinline__ float sigmoidf(float x){ return 1.f/(1.f+expf(-x)); }
__device__ __forceinline__ float lrelu(float x){ return x > 0.f ? x : 0.1f*x; }
__device__ __forceinline__ float b2f(u16t h){ unsigned u = ((unsigned)h)<<16; return __uint_as_float(u); }
__device__ __forceinline__ u16t f2b(float f){
  unsigned u = __float_as_uint(f);
  u += 0x7FFFu + ((u>>16)&1u);
  return (u16t)(u>>16);
}

__device__ __forceinline__ float bilin(const float* __restrict__ img, float ys, float xs, int H, int W){
  float y0f = floorf(ys), x0f = floorf(xs);
  float wy = ys - y0f, wx = xs - x0f;
  int y0 = (int)y0f, x0 = (int)x0f;
  float acc = 0.f;
  #pragma unroll
  for (int dy=0; dy<2; ++dy){
    int yi = y0+dy;
    float wyv = dy ? wy : 1.f-wy;
    if (yi < 0 || yi >= H) continue;
    #pragma unroll
    for (int dx=0; dx<2; ++dx){
      int xi = x0+dx;
      float wxv = dx ? wx : 1.f-wx;
      if (xi < 0 || xi >= W) continue;
      acc += img[yi*W+xi]*(wyv*wxv);
    }
  }
  return acc;
}

// ---------- zero the 1-px border of a dim x dim x C padded NHWC buffer ----------
__global__ __launch_bounds__(256) void padzero2(u16t* buf, int C, int dim, size_t imgStride){
  int n = blockIdx.y;
  int total = (4*dim - 4)*C;
  for (int id = blockIdx.x*256 + threadIdx.x; id < total; id += gridDim.x*256){
    int cell = id / C, c = id % C;
    int d2 = dim - 1;
    int r, col;
    if (cell < dim){ r = 0; col = cell; }
    else if (cell < 2*dim){ r = d2; col = cell - dim; }
    else if (cell < 3*dim - 2){ r = cell - 2*dim + 1; col = 0; }
    else { r = cell - (3*dim - 2) + 1; col = d2; }
    buf[(size_t)n*imgStride + ((size_t)r*dim + col)*C + c] = 0;
  }
}

// ---------- pack conv weights (OIHW fp32) into MFMA B-fragment order bf16 ----------
// layout: [tap][kc][nt][lane][8];  c = kc*32 + (lane>>4)*8 + j; o = nt*16 + (lane&15)
__global__ __launch_bounds__(256) void pack_w(const float* __restrict__ w, u16t* __restrict__ pk,
                                              int Cin, int Cout, int NT, int total){
  int id = blockIdx.x*256 + threadIdx.x;
  if (id >= total) return;
  int j = id & 7, l = (id>>3) & 63;
  int r = id >> 9;
  int nt = r % NT; r /= NT;
  int KC = Cin >> 5;
  int kc = r % KC; int tap = r / KC;
  int c = kc*32 + ((l>>4)<<3) + j;
  int o = nt*16 + (l&15);
  float v = (o < Cout) ? w[((size_t)o*Cin + c)*9 + tap] : 0.f;
  pk[id] = f2b(v);
}

// ---------- conv1: 1->64ch 3x3, fp32 math, writes padded NHWC bf16 ----------
__global__ __launch_bounds__(256) void conv1_k(const float* __restrict__ in, const float* __restrict__ w,
                                               const float* __restrict__ bias, u16t* __restrict__ outp){
  __shared__ float sw[576];
  __shared__ float sb[64];
  int tid = threadIdx.x;
  for (int i = tid; i < 576; i += 256) sw[i] = w[i];
  if (tid < 64) sb[tid] = bias[tid];
  __syncthreads();
  int idx = blockIdx.x*256 + tid;
  int n = blockIdx.y;
  int y = idx/IMW, x = idx%IMW;
  const float* ip = in + (size_t)n*HWF;
  float t[9];
  #pragma unroll
  for (int dy = 0; dy < 3; ++dy)
    #pragma unroll
    for (int dx = 0; dx < 3; ++dx){
      int yy = y+dy-1, xx = x+dx-1;
      t[dy*3+dx] = (yy>=0 && yy<IMH && xx>=0 && xx<IMW) ? ip[yy*IMW+xx] : 0.f;
    }
  u16t* op = outp + (size_t)n*(PDIM*PDIM*64) + ((size_t)(y+1)*PDIM + x+1)*64;
  #pragma unroll
  for (int o8 = 0; o8 < 8; ++o8){
    short8 ov;
    #pragma unroll
    for (int j = 0; j < 8; ++j){
      int o = o8*8 + j;
      float acc = sb[o];
      #pragma unroll
      for (int k = 0; k < 9; ++k) acc += t[k]*sw[o*9+k];
      ov[j] = (short)f2b(acc);
    }
    *(short8*)(op + o8*8) = ov;
  }
}

// ---------- generalized MFMA implicit-GEMM 3x3 conv over padded NHWC bf16 ----------
// wave = 16-out-pixel x-strip (M=16) x NT*16 out ch. K = 9 taps x KC*32 ch. No LDS.
// OMODE: 0 = NCHW fp32; 1 = bf16 NHWC padded(+1); 2 = bf16 NHWC tight; 3 = raw fp32 K-split partials.
// SWZ: XCD-band remap of blockIdx.x (requires gridDim.x % 8 == 0).
// blockIdx.y: OMODE==3 -> K-half index; else output-channel group (ntOff = blockIdx.y*NT).
template<int NT, int STREAMS, int KC, int STRIDE, int OMODE, int ACT, int SWZ>
__global__ __launch_bounds__(256) void gconv3(
    const u16t* __restrict__ A0, const u16t* __restrict__ A1,
    const u16t* __restrict__ Bp, const float* __restrict__ bias,
    float* __restrict__ outf, u16t* __restrict__ outb,
    int Cout, int Wout, int strips, int blocksPerImg,
    int pitchIn, int csIn, int coIn, size_t aImgStride,
    size_t outImgStride, int pitchOut, int csOut, int coOut,
    int KCtot, int NTtot)
{
  int bid = blockIdx.x;
  if (SWZ) bid = (bid & 7)*(gridDim.x >> 3) + (bid >> 3);
  const int wave = threadIdx.x >> 6;
  const int lane = threadIdx.x & 63;
  const int img = bid / blocksPerImg;
  const int sid = (bid - img*blocksPerImg)*4 + wave;
  const int y = sid / strips, xs = (sid % strips) * 16;
  const int m = lane & 15, q = lane >> 4;
  const int kh = (OMODE == 3) ? blockIdx.y : 0;
  const int ntOff = (OMODE == 3) ? 0 : blockIdx.y*NT;
  const int kc0 = kh*KC;
  f32x4 acc[STREAMS][NT];
  #pragma unroll
  for (int s = 0; s < STREAMS; ++s)
    #pragma unroll
    for (int nt = 0; nt < NT; ++nt) acc[s][nt] = (f32x4){0.f,0.f,0.f,0.f};

  for (int tap = 0; tap < 9; ++tap){
    int dy = tap/3, dx = tap%3;
    int row = STRIDE*y + dy;
    int col = (STRIDE == 1) ? (xs + m + dx) : (2*(xs + m) + dx);
    size_t abase = (size_t)img*aImgStride + ((size_t)row*pitchIn + col)*csIn + coIn + kc0*32 + q*8;
    const u16t* ap0 = A0 + abase;
    const u16t* ap1 = (STREAMS==2) ? (A1 + abase) : ap0;
    const u16t* bp = Bp + ((size_t)(tap*KCtot + kc0)*NTtot + ntOff)*512 + lane*8;
    #pragma unroll
    for (int kc = 0; kc < KC; ++kc){
      short8 av0 = *(const short8*)(ap0 + kc*32);
      short8 av1;
      if (STREAMS==2) av1 = *(const short8*)(ap1 + kc*32);
      #pragma unroll
      for (int nt = 0; nt < NT; ++nt){
        short8 bv = *(const short8*)(bp + (size_t)(kc*NTtot + nt)*512);
        acc[0][nt] = __builtin_amdgcn_mfma_f32_16x16x32_bf16(av0, bv, acc[0][nt], 0, 0, 0);
        if (STREAMS==2)
          acc[1][nt] = __builtin_amdgcn_mfma_f32_16x16x32_bf16(av1, bv, acc[1][nt], 0, 0, 0);
      }
    }
  }
  // C/D: col = lane&15 (=out ch), row = (lane>>4)*4 + reg (=pixel in strip)
  const int prow0 = q*4;
  if (OMODE == 3){
    #pragma unroll
    for (int nt = 0; nt < NT; ++nt){
      int o = nt*16 + m;
      #pragma unroll
      for (int r = 0; r < 4; ++r){
        int px = xs + prow0 + r;
        if (px >= Wout) continue;
        size_t pix = (size_t)y*Wout + px;
        #pragma unroll
        for (int s = 0; s < STREAMS; ++s)
          outf[((size_t)((kh*2 + s)*64 + o))*((size_t)Wout*Wout) + pix] = acc[s][nt][r];
      }
    }
    return;
  }
  #pragma unroll
  for (int nt = 0; nt < NT; ++nt){
    int o = (ntOff + nt)*16 + m;
    if (o >= Cout) continue;
    float bv = bias[o];
    #pragma unroll
    for (int r = 0; r < 4; ++r){
      int px = xs + prow0 + r;
      if (px >= Wout) continue;
      float v = acc[0][nt][r] + bv;
      if (ACT) v = fmaxf(v, 0.f);
      if (OMODE == 0){
        outf[((size_t)img*Cout + o)*((size_t)Wout*Wout) + (size_t)y*Wout + px] = v;
      } else if (OMODE == 1){
        outb[(size_t)img*outImgStride + ((size_t)(y+1)*pitchOut + px+1)*csOut + coOut + o] = f2b(v);
      } else {
        outb[(size_t)img*outImgStride + ((size_t)y*pitchOut + px)*csOut + coOut + o] = f2b(v);
      }
    }
  }
}

// ---------- combine fuse K-split partials: out0 = 0.1*lrelu(ps+b) + lrelu(pf+b) ----------
__global__ __launch_bounds__(256) void fuse_combine(const float* __restrict__ P,
    const float* __restrict__ bias, u16t* __restrict__ outp){
  __shared__ float sb[64];
  if (threadIdx.x < 64) sb[threadIdx.x] = bias[threadIdx.x];
  __syncthreads();
  int idx = blockIdx.x*256 + threadIdx.x;
  int y = idx/IMW, x = idx%IMW;
  u16t* op = outp + ((size_t)(y+1)*PDIM + x+1)*64;
  #pragma unroll
  for (int o8 = 0; o8 < 8; ++o8){
    short8 ov;
    #pragma unroll
    for (int j = 0; j < 8; ++j){
      int o = o8*8 + j;
      float b = sb[o];
      float ps = P[(size_t)(o)*HWF + idx]      + P[(size_t)(128+o)*HWF + idx];
      float pf = P[(size_t)(64+o)*HWF + idx]   + P[(size_t)(192+o)*HWF + idx];
      float v = 0.1f*lrelu(ps + b) + lrelu(pf + b);
      ov[j] = (short)f2b(v);
    }
    *(short8*)(op + o8*8) = ov;
  }
}

// ---------- gating + flow-warp, channels-last bf16 ----------
__global__ __launch_bounds__(256) void gate_nhwc(
    const u16t* __restrict__ fpad, const u16t* __restrict__ pred,
    const float* __restrict__ mv, u16t* __restrict__ spad)
{
  int idx = blockIdx.x*256 + threadIdx.x;
  int t = blockIdx.y;
  int y = idx/IMW, x = idx%IMW;
  size_t pc = ((size_t)(y+1)*PDIM + (x+1))*448;
  const u16t* rp = fpad + pc + 192;                 // ref = feat t=3
  const u16t* pp = pred + ((size_t)t*HWF + idx)*64;
  u16t* sp = spad + pc + (size_t)t*64;
  const u16t* tp[4]; float tw[4];
  if (t == 0){
    tp[0] = fpad + pc; tw[0] = 1.f;
    tp[1] = tp[2] = tp[3] = fpad + pc; tw[1] = tw[2] = tw[3] = 0.f;
  } else {
    float fx = mv[(((size_t)(t-1)*HWF + idx))*2 + 0];
    float fy = mv[(((size_t)(t-1)*HWF + idx))*2 + 1];
    float ys = (float)y + fy, xs = (float)x + fx;
    float y0f = floorf(ys), x0f = floorf(xs);
    float wy = ys - y0f, wx = xs - x0f;
    int y0 = (int)y0f, x0i = (int)x0f;
    int k = 0;
    #pragma unroll
    for (int dy2 = 0; dy2 < 2; ++dy2)
      #pragma unroll
      for (int dx2 = 0; dx2 < 2; ++dx2){
        int yi = y0+dy2, xi = x0i+dx2;
        float wv = (dy2 ? wy : 1.f-wy)*(dx2 ? wx : 1.f-wx);
        bool ok = (yi >= 0 && yi <= 191 && xi >= 0 && xi <= 191);
        int yc = min(max(yi,0),191), xc = min(max(xi,0),191);
        tp[k] = fpad + ((size_t)(yc+1)*PDIM + xc+1)*448 + (size_t)(t-1)*64;
        tw[k] = ok ? wv : 0.f;
        ++k;
      }
  }
  #pragma unroll
  for (int c8 = 0; c8 < 8; ++c8){
    short8 rv = *(const short8*)(rp + c8*8);
    short8 pv = *(const short8*)(pp + c8*8);
    short8 t0v = *(const short8*)(tp[0] + c8*8);
    short8 t1v = *(const short8*)(tp[1] + c8*8);
    short8 t2v = *(const short8*)(tp[2] + c8*8);
    short8 t3v = *(const short8*)(tp[3] + c8*8);
    short8 ov;
    #pragma unroll
    for (int j = 0; j < 8; ++j){
      float r = b2f((u16t)rv[j]);
      float p = b2f((u16t)pv[j]);
      float a = tw[0]*b2f((u16t)t0v[j]) + tw[1]*b2f((u16t)t1v[j])
              + tw[2]*b2f((u16t)t2v[j]) + tw[3]*b2f((u16t)t3v[j]);
      float sv = a*sigmoidf(a*r) + p*sigmoidf(p*r);
      ov[j] = (short)f2b(sv);
    }
    *(short8*)(sp + c8*8) = ov;
  }
}

// ---------------- convT 4x4 s2 p1 (+relu): parity-decomposed, fp32 in, bf16 NHWC out ----------------
__global__ __launch_bounds__(256) void repack_convT_w(const float* __restrict__ w, float* __restrict__ wp){
  int id = blockIdx.x*256 + threadIdx.x;
  int par = id >> 12, o = (id >> 6) & 63, i = id & 63;
  int ry = par >> 1, rx = par & 1;
  #pragma unroll
  for (int jy = 0; jy < 2; ++jy)
    #pragma unroll
    for (int jx = 0; jx < 2; ++jx){
      int ka = 3 - ry - 2*jy, kb = 3 - rx - 2*jx;
      wp[((size_t)((par*64 + o)*64 + i))*4 + jy*2 + jx] = w[((size_t)(i*64 + o))*16 + ka*4 + kb];
    }
}

__global__ __launch_bounds__(256) void convT_tile2(
    const float* __restrict__ in, const float* __restrict__ wp,
    const float* __restrict__ bias, u16t* __restrict__ outb,
    int Hin, int tilesX, int pitchOut, int csOut, int coOut)
{
  const int CC = 4;
  __shared__ float sIn[CC][10*11];
  __shared__ float sW[16][CC][4][4];
  const int Win = Hin;
  const int o0 = blockIdx.x*16;
  const int tile = blockIdx.y;
  const int ty0 = (tile/tilesX)*16, tx0 = (tile%tilesX)*16;
  const int tid = threadIdx.x;
  const int py = tid>>4, px = tid&15;
  const int ry = py&1, rx = px&1, par = ry*2 + rx;
  const int lr = py>>1, lc = px>>1;
  const int r0 = ty0>>1, c0 = tx0>>1;
  float acc[16] = {};
  for (int ib = 0; ib < 64; ib += CC){
    for (int i = tid; i < CC*100; i += 256){
      int c = i/100, rem = i%100, r = rem/10, col = rem%10;
      int gy = r0 - 1 + r, gx = c0 - 1 + col;
      float v = 0.f;
      if (gy >= 0 && gy < Hin && gx >= 0 && gx < Win)
        v = in[(size_t)(ib + c)*Hin*Win + gy*Win + gx];
      sIn[c][r*11 + col] = v;
    }
    for (int i = tid; i < 1024; i += 256){
      int ol = i >> 6, rem = i & 63, ci = rem >> 4, p2 = (rem >> 2) & 3, j = rem & 3;
      sW[ol][ci][p2][j] = wp[((size_t)((p2*64 + o0 + ol)*64) + ib + ci)*4 + j];
    }
    __syncthreads();
    #pragma unroll
    for (int ci = 0; ci < CC; ++ci){
      int rb = lr + ry, cb = lc + rx;
      float t00 = sIn[ci][rb*11 + cb],     t01 = sIn[ci][rb*11 + cb + 1];
      float t10 = sIn[ci][(rb+1)*11 + cb], t11 = sIn[ci][(rb+1)*11 + cb + 1];
      #pragma unroll
      for (int ol = 0; ol < 16; ++ol){
        const float* wv = &sW[ol][ci][par][0];
        acc[ol] += t00*wv[0] + t01*wv[1] + t10*wv[2] + t11*wv[3];
      }
    }
    __syncthreads();
  }
  int gy = ty0 + py, gx = tx0 + px;
  u16t* op = outb + ((size_t)(gy+1)*pitchOut + gx+1)*csOut + coOut + o0;
  short8 pa, pb;
  #pragma unroll
  for (int i = 0; i < 8; ++i) pa[i] = (short)f2b(fmaxf(acc[i] + bias[o0+i], 0.f));
  #pragma unroll
  for (int i = 0; i < 8; ++i) pb[i] = (short)f2b(fmaxf(acc[8+i] + bias[o0+8+i], 0.f));
  *(short8*)op = pa;
  *(short8*)(op + 8) = pb;
}

// ---------------- deformable conv ----------------
__global__ __launch_bounds__(256) void deform_sample_k(
    const float* __restrict__ lqs, const float* __restrict__ om,
    float* __restrict__ vbuf)
{
  int idx = blockIdx.x*256 + threadIdx.x;
  int g = blockIdx.y;
  int h = idx / IMW, x = idx % IMW;
  const float* img = lqs + (size_t)g*HWF;
  #pragma unroll
  for (int k = 0; k < 9; ++k){
    int j = g*9 + k;
    float offy = om[(size_t)(j*2 + 0)*HWF + idx];
    float offx = om[(size_t)(j*2 + 1)*HWF + idx];
    float m = sigmoidf(om[(size_t)(126 + j)*HWF + idx]);
    float ys = (float)(h + (k/3) - 1) + offy;
    float xs = (float)(x + (k%3) - 1) + offx;
    vbuf[(size_t)j*HWF + idx] = bilin(img, ys, xs, IMH, IMW) * m;
  }
}

__global__ __launch_bounds__(256) void deform_out_k(
    const float* __restrict__ vbuf, const float* __restrict__ dcw,
    const float* __restrict__ dcb, float* __restrict__ out)
{
  __shared__ float sw[16*63];
  int idx = blockIdx.x*256 + threadIdx.x;
  int o0 = blockIdx.y*16;
  for (int i = threadIdx.x; i < 16*63; i += 256)
    sw[i] = dcw[(size_t)o0*63 + i];
  __syncthreads();
  float v[63];
  #pragma unroll
  for (int j = 0; j < 63; ++j) v[j] = vbuf[(size_t)j*HWF + idx];
  for (int ol = 0; ol < 16; ++ol){
    float acc = dcb[o0 + ol];
    #pragma unroll
    for (int j = 0; j < 63; ++j) acc += v[j]*sw[ol*63 + j];
    out[(size_t)(o0 + ol)*HWF + idx] = fmaxf(acc, 0.f);
  }
}

extern "C" void kernel_launch(void* const* d_in, const int* in_sizes, int n_in,
                              void* d_out, int out_size, void* d_ws, size_t ws_size,
                              hipStream_t stream)
{
  const float* lqs   = (const float*)d_in[0];
  const float* preds = (const float*)d_in[1];
  const float* mv    = (const float*)d_in[2];
  const float* bw1   = (const float*)d_in[3];
  const float* bb1   = (const float*)d_in[4];
  const float* bw2   = (const float*)d_in[5];
  const float* bb2   = (const float*)d_in[6];
  const float* dn1w  = (const float*)d_in[7];
  const float* dn1b  = (const float*)d_in[8];
  const float* dn2w  = (const float*)d_in[9];
  const float* dn2b  = (const float*)d_in[10];
  const float* up1cw = (const float*)d_in[11];
  const float* up1cb = (const float*)d_in[12];
  const float* up1tw = (const float*)d_in[13];
  const float* up1tb = (const float*)d_in[14];
  const float* up2cw = (const float*)d_in[15];
  const float* up2cb = (const float*)d_in[16];
  const float* up2tw = (const float*)d_in[17];
  const float* up2tb = (const float*)d_in[18];
  const float* trcw  = (const float*)d_in[19];
  const float* trcb  = (const float*)d_in[20];
  const float* trtw  = (const float*)d_in[21];
  const float* trtb  = (const float*)d_in[22];
  const float* ffw   = (const float*)d_in[23];
  const float* ffb   = (const float*)d_in[24];
  const float* omw   = (const float*)d_in[25];
  const float* omb   = (const float*)d_in[26];
  const float* dcw   = (const float*)d_in[27];
  const float* dcb   = (const float*)d_in[28];
  float* outp = (float*)d_out;

  char* p = (char*)d_ws;
  const size_t PIMG64 = (size_t)PDIM*PDIM*64;
  u16t* bbpad    = (u16t*)p; p += 7*PIMG64*2;                 // conv1 out; later spad; later featfpad
  u16t* fpad     = (u16t*)p; p += (size_t)PDIM*PDIM*448*2;    // feat NHWC448; later vbuf (fp32)
  u16t* prednhwc = (u16t*)p; p += (size_t)7*HWF*64*2;         // pred NHWC64; later om (fp32)
  u16t* out0pad  = (u16t*)p; p += (size_t)PDIM*PDIM*64*2;     // fuse out, padded NHWC64
  u16t* cat1pad  = (u16t*)p; p += (size_t)98*98*128*2;        // [u2t | out1], padded NHWC128
  u16t* cat2pad  = (u16t*)p; p += (size_t)50*50*128*2;        // [t1 | out2], padded NHWC128
  float* t0      = (float*)p; p += (size_t)24*24*64*4;
  float* u2      = (float*)p; p += (size_t)48*48*64*4;
  float* u1      = (float*)p; p += (size_t)96*96*64*4;
  u16t* ffwpack  = (u16t*)p; p += 258048*2;
  u16t* c2pack   = (u16t*)p; p += 36864*2;
  u16t* ompack   = (u16t*)p; p += 110592*2;
  u16t* dn1pack  = (u16t*)p; p += 36864*2;
  u16t* dn2pack  = (u16t*)p; p += 36864*2;
  u16t* trcpack  = (u16t*)p; p += 36864*2;
  u16t* up2cpack = (u16t*)p; p += 73728*2;
  u16t* up1cpack = (u16t*)p; p += 73728*2;
  float* wp0     = (float*)p; p += 65536*4;
  float* wp1     = (float*)p; p += 65536*4;
  float* wp2     = (float*)p; p += 65536*4;
  float* fpart   = (float*)p; p += (size_t)256*HWF*4;         // 4x64-plane fp32 fuse partials

  u16t* spad = bbpad;         // [194][194][448] after backbone done
  u16t* featfpad = bbpad;     // [194][194][64] after fuse done
  float* om = (float*)prednhwc;
  float* vbuf = (float*)fpad;

  dim3 blk(256);
  // weight packs
  pack_w<<<dim3(1008), blk, 0, stream>>>(ffw,   ffwpack,  448, 64, 4, 258048);
  pack_w<<<dim3(144),  blk, 0, stream>>>(bw2,   c2pack,    64, 64, 4, 36864);
  pack_w<<<dim3(432),  blk, 0, stream>>>(omw,   ompack,    64, 189, 12, 110592);
  pack_w<<<dim3(144),  blk, 0, stream>>>(dn1w,  dn1pack,   64, 64, 4, 36864);
  pack_w<<<dim3(144),  blk, 0, stream>>>(dn2w,  dn2pack,   64, 64, 4, 36864);
  pack_w<<<dim3(144),  blk, 0, stream>>>(trcw,  trcpack,   64, 64, 4, 36864);
  pack_w<<<dim3(288),  blk, 0, stream>>>(up2cw, up2cpack, 128, 64, 4, 73728);
  pack_w<<<dim3(288),  blk, 0, stream>>>(up1cw, up1cpack, 128, 64, 4, 73728);
  repack_convT_w<<<dim3(64), blk, 0, stream>>>(trtw,  wp0);
  repack_convT_w<<<dim3(64), blk, 0, stream>>>(up2tw, wp1);
  repack_convT_w<<<dim3(64), blk, 0, stream>>>(up1tw, wp2);
  // pad borders
  padzero2<<<dim3(194,7), blk, 0, stream>>>(bbpad, 64, PDIM, PIMG64);
  padzero2<<<dim3(1352,1), blk, 0, stream>>>(fpad, 448, PDIM, 0);
  padzero2<<<dim3(194,1), blk, 0, stream>>>(out0pad, 64, PDIM, 0);
  padzero2<<<dim3(194,1), blk, 0, stream>>>(cat1pad, 128, 98, 0);
  padzero2<<<dim3(98,1),  blk, 0, stream>>>(cat2pad, 128, 50, 0);
  // backbone lqs -> fpad (NHWC448 padded; per-img channel offset via outImgStride=64)
  conv1_k<<<dim3(144,7), blk, 0, stream>>>(lqs, bw1, bb1, bbpad);
  gconv3<4,1,2,1,1,0,1><<<dim3(4032,1,1), blk, 0, stream>>>(bbpad, nullptr, c2pack, bb2, nullptr, fpad,
      64, 192, 12, 576, PDIM, 64, 0, PIMG64, 64, PDIM, 448, 0, 2, 4);
  // backbone preds -> prednhwc (NHWC64 tight)
  conv1_k<<<dim3(144,7), blk, 0, stream>>>(preds, bw1, bb1, bbpad);
  gconv3<4,1,2,1,2,0,1><<<dim3(4032,1,1), blk, 0, stream>>>(bbpad, nullptr, c2pack, bb2, nullptr, prednhwc,
      64, 192, 12, 576, PDIM, 64, 0, PIMG64, (size_t)HWF*64, 192, 64, 0, 2, 4);
  // gate (+warp) -> spad (reuses bbpad region)
  padzero2<<<dim3(1352,1), blk, 0, stream>>>(spad, 448, PDIM, 0);
  gate_nhwc<<<dim3(144,7), blk, 0, stream>>>(fpad, prednhwc, mv, spad);
  // fused dual conv, K-split x2 -> fp32 partials -> combine to out0pad
  gconv3<4,2,7,1,3,0,1><<<dim3(576,2,1), blk, 0, stream>>>(spad, fpad, ffwpack, ffb, fpart, nullptr,
      64, 192, 12, 576, PDIM, 448, 0, 0, 0, 0, 0, 0, 14, 4);
  fuse_combine<<<dim3(144), blk, 0, stream>>>(fpart, ffb, out0pad);
  // U-Net: downs (stride-2 MFMA), writing into concat halves
  gconv3<4,1,2,2,1,1,1><<<dim3(144,1,1), blk, 0, stream>>>(out0pad, nullptr, dn1pack, dn1b, nullptr, cat1pad,
      64, 96, 6, 144, PDIM, 64, 0, 0, 0, 98, 128, 64, 2, 4);       // out1 -> cat1[64:]
  gconv3<4,1,2,2,1,1,0><<<dim3(36,1,1), blk, 0, stream>>>(cat1pad, nullptr, dn2pack, dn2b, nullptr, cat2pad,
      64, 48, 3, 36, 98, 128, 64, 0, 0, 50, 128, 64, 2, 4);        // out2 -> cat2[64:]
  gconv3<4,1,2,2,0,1,0><<<dim3(12,1,1), blk, 0, stream>>>(cat2pad, nullptr, trcpack, trcb, t0, nullptr,
      64, 24, 2, 12, 50, 128, 64, 0, 0, 0, 0, 0, 2, 4);            // t0 (fp32 NCHW)
  convT_tile2<<<dim3(4,9), blk, 0, stream>>>(t0, wp0, trtb, cat2pad, 24, 3, 50, 128, 0);   // t1 -> cat2[:64]
  gconv3<4,1,4,1,0,1,0><<<dim3(36,1,1), blk, 0, stream>>>(cat2pad, nullptr, up2cpack, up2cb, u2, nullptr,
      64, 48, 3, 36, 50, 128, 0, 0, 0, 0, 0, 0, 4, 4);             // u2 (fp32 NCHW)
  convT_tile2<<<dim3(4,36), blk, 0, stream>>>(u2, wp1, up2tb, cat1pad, 48, 6, 98, 128, 0); // u2t -> cat1[:64]
  gconv3<4,1,4,1,0,1,1><<<dim3(144,1,1), blk, 0, stream>>>(cat1pad, nullptr, up1cpack, up1cb, u1, nullptr,
      64, 96, 6, 144, 98, 128, 0, 0, 0, 0, 0, 0, 4, 4);            // u1 (fp32 NCHW)
  // final convT writes featfpad (reuses bbpad/spad region, dead after fuse)
  padzero2<<<dim3(194,1), blk, 0, stream>>>(featfpad, 64, PDIM, 0);
  convT_tile2<<<dim3(4,144), blk, 0, stream>>>(u1, wp2, up1tb, featfpad, 96, 12, PDIM, 64, 0);
  // offsets/masks conv (64 -> 189), NT-split x3 -> om (fp32 NCHW, reuses prednhwc region)
  gconv3<4,1,2,1,0,0,1><<<dim3(576,3,1), blk, 0, stream>>>(featfpad, nullptr, ompack, omb, om, nullptr,
      189, 192, 12, 576, PDIM, 64, 0, 0, 0, 0, 0, 0, 2, 12);
  // deformable conv
  deform_sample_k<<<dim3(144,7), blk, 0, stream>>>(lqs, om, vbuf);
  deform_out_k<<<dim3(144,4), blk, 0, stream>>>(vbuf, dcw, dcb, outp);
}

// Round 6
// 758.289 us; speedup vs baseline: 1.2508x; 1.2508x over previous
//
#include <hip/hip_runtime.h>
#include <math.h>

#define IMH 192
#define IMW 192
#define HWF 36864
#define PDIM 194

typedef unsigned short u16t;
typedef __attribute__((ext_vector_type(8))) short short8;
typedef __attribute__((ext_vector_type(4))) float f32x4;

__device__ __forceinline__ float sigmoidf(float x){ return 1.f/(1.f+expf(-x)); }
__device__ __forceinline__ float lrelu(float x){ return x > 0.f ? x : 0.1f*x; }
__device__ __forceinline__ float b2f(u16t h){ unsigned u = ((unsigned)h)<<16; return __uint_as_float(u); }
__device__ __forceinline__ u16t f2b(float f){
  unsigned u = __float_as_uint(f);
  u += 0x7FFFu + ((u>>16)&1u);
  return (u16t)(u>>16);
}

__device__ __forceinline__ float bilin(const float* __restrict__ img, float ys, float xs, int H, int W){
  float y0f = floorf(ys), x0f = floorf(xs);
  float wy = ys - y0f, wx = xs - x0f;
  int y0 = (int)y0f, x0 = (int)x0f;
  float acc = 0.f;
  #pragma unroll
  for (int dy=0; dy<2; ++dy){
    int yi = y0+dy;
    float wyv = dy ? wy : 1.f-wy;
    if (yi < 0 || yi >= H) continue;
    #pragma unroll
    for (int dx=0; dx<2; ++dx){
      int xi = x0+dx;
      float wxv = dx ? wx : 1.f-wx;
      if (xi < 0 || xi >= W) continue;
      acc += img[yi*W+xi]*(wyv*wxv);
    }
  }
  return acc;
}

// ================= descriptor-driven setup kernels =================
struct PkD { const float* w; u16t* dst; int Cin, Cout, NT, total; };
struct PkD8 { PkD d[8]; };
// pack conv weights (OIHW fp32) -> [tap][kc][nt][lane][8] bf16
__global__ __launch_bounds__(256) void pack_all(PkD8 ds){
  PkD d = ds.d[blockIdx.y];
  int id = blockIdx.x*256 + threadIdx.x;
  if (id >= d.total) return;
  int j = id & 7, l = (id>>3) & 63;
  int r = id >> 9;
  int nt = r % d.NT; r /= d.NT;
  int KC = d.Cin >> 5;
  int kc = r % KC; int tap = r / KC;
  int c = kc*32 + ((l>>4)<<3) + j;
  int o = nt*16 + (l&15);
  float v = (o < d.Cout) ? d.w[((size_t)o*d.Cin + c)*9 + tap] : 0.f;
  d.dst[id] = f2b(v);
}

struct RpD { const float* w; float* wp; };
struct RpD3 { RpD d[3]; };
__global__ __launch_bounds__(256) void repack_all(RpD3 ds){
  RpD d = ds.d[blockIdx.y];
  int id = blockIdx.x*256 + threadIdx.x;
  int par = id >> 12, o = (id >> 6) & 63, i = id & 63;
  int ry = par >> 1, rx = par & 1;
  #pragma unroll
  for (int jy = 0; jy < 2; ++jy)
    #pragma unroll
    for (int jx = 0; jx < 2; ++jx){
      int ka = 3 - ry - 2*jy, kb = 3 - rx - 2*jx;
      d.wp[((size_t)((par*64 + o)*64 + i))*4 + jy*2 + jx] = d.w[((size_t)(i*64 + o))*16 + ka*4 + kb];
    }
}

struct PzD { u16t* buf; int C, dim, nimg; size_t stride; };
struct PzD5 { PzD d[5]; };
__global__ __launch_bounds__(256) void padzero_all(PzD5 ds){
  PzD d = ds.d[blockIdx.y];
  int per = (4*d.dim - 4)*d.C;
  long total = (long)per*d.nimg;
  for (long id = (long)blockIdx.x*256 + threadIdx.x; id < total; id += (long)gridDim.x*256){
    int n = (int)(id / per), c2 = (int)(id % per);
    int cell = c2 / d.C, c = c2 % d.C;
    int d2 = d.dim - 1;
    int r, col;
    if (cell < d.dim){ r = 0; col = cell; }
    else if (cell < 2*d.dim){ r = d2; col = cell - d.dim; }
    else if (cell < 3*d.dim - 2){ r = cell - 2*d.dim + 1; col = 0; }
    else { r = cell - (3*d.dim - 2) + 1; col = d2; }
    d.buf[(size_t)n*d.stride + ((size_t)r*d.dim + col)*d.C + c] = 0;
  }
}

// single-buffer padzero (for region-reuse points mid-graph)
__global__ __launch_bounds__(256) void padzero2(u16t* buf, int C, int dim){
  int total = (4*dim - 4)*C;
  for (int id = blockIdx.x*256 + threadIdx.x; id < total; id += gridDim.x*256){
    int cell = id / C, c = id % C;
    int d2 = dim - 1;
    int r, col;
    if (cell < dim){ r = 0; col = cell; }
    else if (cell < 2*dim){ r = d2; col = cell - dim; }
    else if (cell < 3*dim - 2){ r = cell - 2*dim + 1; col = 0; }
    else { r = cell - (3*dim - 2) + 1; col = d2; }
    buf[((size_t)r*dim + col)*C + c] = 0;
  }
}

// ---------- conv1: 1->64ch 3x3, fp32 math, writes padded NHWC bf16; 14 imgs ----------
__global__ __launch_bounds__(256) void conv1_k(const float* __restrict__ lqs, const float* __restrict__ preds,
                                               const float* __restrict__ w,
                                               const float* __restrict__ bias, u16t* __restrict__ outp){
  __shared__ float sw[576];
  __shared__ float sb[64];
  int tid = threadIdx.x;
  for (int i = tid; i < 576; i += 256) sw[i] = w[i];
  if (tid < 64) sb[tid] = bias[tid];
  __syncthreads();
  int idx = blockIdx.x*256 + tid;
  int n = blockIdx.y;
  int y = idx/IMW, x = idx%IMW;
  const float* ip = (n < 7) ? (lqs + (size_t)n*HWF) : (preds + (size_t)(n-7)*HWF);
  float t[9];
  #pragma unroll
  for (int dy = 0; dy < 3; ++dy)
    #pragma unroll
    for (int dx = 0; dx < 3; ++dx){
      int yy = y+dy-1, xx = x+dx-1;
      t[dy*3+dx] = (yy>=0 && yy<IMH && xx>=0 && xx<IMW) ? ip[yy*IMW+xx] : 0.f;
    }
  u16t* op = outp + (size_t)n*(PDIM*PDIM*64) + ((size_t)(y+1)*PDIM + x+1)*64;
  #pragma unroll
  for (int o8 = 0; o8 < 8; ++o8){
    short8 ov;
    #pragma unroll
    for (int j = 0; j < 8; ++j){
      int o = o8*8 + j;
      float acc = sb[o];
      #pragma unroll
      for (int k = 0; k < 9; ++k) acc += t[k]*sw[o*9+k];
      ov[j] = (short)f2b(acc);
    }
    *(short8*)(op + o8*8) = ov;
  }
}

// ========== LDS-staged MFMA implicit-GEMM 3x3 stride-1 conv (Cout=64) ==========
// Block = 4 waves = 4-row x 16-px x 64-ch output tile. Per 32-ch K-chunk the block
// stages its 6x18-px input tile in LDS (pixel stride 40 shorts = 80 B); 9 taps read LDS.
// Wave shape: 32 px (2 rows) x 32 ch (2 nt) -> halves B L2 traffic vs 16x64.
// OMODE: 3 = fp32 K-split partials (fuse; blockIdx.y = K-half); 12 = backbone runtime
// select (img<7 -> fpad NHWC448 padded, else prednhwc NHWC64 tight).
template<int STREAMS, int KC, int OMODE, int SWZ>
__global__ __launch_bounds__(256) void cgemm(
    const u16t* __restrict__ A0, const u16t* __restrict__ A1,
    const u16t* __restrict__ Bp, const float* __restrict__ bias,
    float* __restrict__ outf, u16t* __restrict__ outb, u16t* __restrict__ outb2,
    int blocksPerImg, int pitchIn, int csIn, size_t aImgStride, int KCtot)
{
  __shared__ u16t sA[STREAMS*108*40];
  int bid = blockIdx.x;
  if (SWZ) bid = (bid & 7)*(gridDim.x >> 3) + (bid >> 3);
  const int tid = threadIdx.x;
  const int wave = tid >> 6, lane = tid & 63;
  const int m = lane & 15, q = lane >> 4;
  const int img = bid / blocksPerImg;
  const int rem = bid - img*blocksPerImg;
  const int yg = rem / 12, xsg = rem % 12;
  const int y0 = yg*4, xs = xsg*16;
  const int rp = wave >> 1, np = wave & 1;    // row-pair, nt-pair
  const int kc0 = (OMODE == 3) ? blockIdx.y*KC : 0;
  f32x4 acc[STREAMS][2][2];
  #pragma unroll
  for (int s = 0; s < STREAMS; ++s)
    #pragma unroll
    for (int r = 0; r < 2; ++r)
      #pragma unroll
      for (int n = 0; n < 2; ++n) acc[s][r][n] = (f32x4){0.f,0.f,0.f,0.f};

  #pragma unroll 1
  for (int kc = 0; kc < KC; ++kc){
    const int kca = kc0 + kc;
    if (kc) __syncthreads();
    // ---- stage 6x18 px x 32 ch (x STREAMS) into LDS ----
    for (int u = tid; u < STREAMS*216; u += 256){
      int st = u/216, r2 = u%216, p = r2>>1, h = r2&1;
      int rr = p/18, cc = p%18;
      size_t ga = (size_t)img*aImgStride + ((size_t)(y0+rr)*pitchIn + xs+cc)*csIn + kca*32 + h*16;
      const u16t* gp = ((STREAMS==2 && st==1) ? A1 : A0) + ga;
      short8 v0 = *(const short8*)gp;
      short8 v1 = *(const short8*)(gp + 8);
      u16t* lp = &sA[((size_t)(st*108 + p))*40 + h*16];
      *(short8*)lp = v0;
      *(short8*)(lp+8) = v1;
    }
    __syncthreads();
    // ---- 9 taps from LDS ----
    #pragma unroll
    for (int tap = 0; tap < 9; ++tap){
      const int dy = tap/3, dx = tap%3;
      short8 af[STREAMS][2];
      #pragma unroll
      for (int st = 0; st < STREAMS; ++st)
        #pragma unroll
        for (int r = 0; r < 2; ++r)
          af[st][r] = *(const short8*)&sA[((size_t)(st*108 + (2*rp + r + dy)*18 + dx + m))*40 + q*8];
      const u16t* bp = Bp + ((size_t)(tap*KCtot + kca)*4 + np*2)*512 + lane*8;
      short8 b0 = *(const short8*)bp;
      short8 b1 = *(const short8*)(bp + 512);
      #pragma unroll
      for (int st = 0; st < STREAMS; ++st)
        #pragma unroll
        for (int r = 0; r < 2; ++r){
          acc[st][r][0] = __builtin_amdgcn_mfma_f32_16x16x32_bf16(af[st][r], b0, acc[st][r][0], 0, 0, 0);
          acc[st][r][1] = __builtin_amdgcn_mfma_f32_16x16x32_bf16(af[st][r], b1, acc[st][r][1], 0, 0, 0);
        }
    }
  }
  // ---- epilogue. C/D: col=lane&15 (out ch), row=q*4+reg (pixel in strip) ----
  const int px0 = q*4;
  #pragma unroll
  for (int r = 0; r < 2; ++r){
    int yout = y0 + 2*rp + r;
    #pragma unroll
    for (int n = 0; n < 2; ++n){
      int o = (np*2 + n)*16 + m;
      if (OMODE == 3){
        #pragma unroll
        for (int g = 0; g < 4; ++g){
          int px = xs + px0 + g;
          size_t pix = (size_t)yout*IMW + px;
          #pragma unroll
          for (int st = 0; st < STREAMS; ++st)
            outf[((size_t)((blockIdx.y*2 + st)*64 + o))*HWF + pix] = acc[st][r][n][g];
        }
      } else {
        float bv = bias[o];
        #pragma unroll
        for (int g = 0; g < 4; ++g){
          int px = xs + px0 + g;
          float v = acc[0][r][n][g] + bv;
          if (img < 7)
            outb[((size_t)(yout+1)*PDIM + px+1)*448 + (size_t)img*64 + o] = f2b(v);
          else
            outb2[(size_t)(img-7)*((size_t)HWF*64) + ((size_t)yout*IMW + px)*64 + o] = f2b(v);
        }
      }
    }
  }
}

// ---------- no-LDS MFMA implicit-GEMM (U-Net smalls, om conv) ----------
template<int NT, int STREAMS, int KC, int STRIDE, int OMODE, int ACT, int SWZ>
__global__ __launch_bounds__(256) void gconv3(
    const u16t* __restrict__ A0, const u16t* __restrict__ A1,
    const u16t* __restrict__ Bp, const float* __restrict__ bias,
    float* __restrict__ outf, u16t* __restrict__ outb,
    int Cout, int Wout, int strips, int blocksPerImg,
    int pitchIn, int csIn, int coIn, size_t aImgStride,
    size_t outImgStride, int pitchOut, int csOut, int coOut,
    int KCtot, int NTtot)
{
  int bid = blockIdx.x;
  if (SWZ) bid = (bid & 7)*(gridDim.x >> 3) + (bid >> 3);
  const int wave = threadIdx.x >> 6;
  const int lane = threadIdx.x & 63;
  const int img = bid / blocksPerImg;
  const int sid = (bid - img*blocksPerImg)*4 + wave;
  const int y = sid / strips, xs = (sid % strips) * 16;
  const int m = lane & 15, q = lane >> 4;
  const int ntOff = blockIdx.y*NT;
  f32x4 acc[STREAMS][NT];
  #pragma unroll
  for (int s = 0; s < STREAMS; ++s)
    #pragma unroll
    for (int nt = 0; nt < NT; ++nt) acc[s][nt] = (f32x4){0.f,0.f,0.f,0.f};

  for (int tap = 0; tap < 9; ++tap){
    int dy = tap/3, dx = tap%3;
    int row = STRIDE*y + dy;
    int col = (STRIDE == 1) ? (xs + m + dx) : (2*(xs + m) + dx);
    size_t abase = (size_t)img*aImgStride + ((size_t)row*pitchIn + col)*csIn + coIn + q*8;
    const u16t* ap0 = A0 + abase;
    const u16t* bp = Bp + ((size_t)(tap*KCtot)*NTtot + ntOff)*512 + lane*8;
    #pragma unroll
    for (int kc = 0; kc < KC; ++kc){
      short8 av0 = *(const short8*)(ap0 + kc*32);
      #pragma unroll
      for (int nt = 0; nt < NT; ++nt){
        short8 bv = *(const short8*)(bp + (size_t)(kc*NTtot + nt)*512);
        acc[0][nt] = __builtin_amdgcn_mfma_f32_16x16x32_bf16(av0, bv, acc[0][nt], 0, 0, 0);
      }
    }
  }
  const int prow0 = q*4;
  #pragma unroll
  for (int nt = 0; nt < NT; ++nt){
    int o = (ntOff + nt)*16 + m;
    if (o >= Cout) continue;
    float bv = bias[o];
    #pragma unroll
    for (int r = 0; r < 4; ++r){
      int px = xs + prow0 + r;
      if (px >= Wout) continue;
      float v = acc[0][nt][r] + bv;
      if (ACT) v = fmaxf(v, 0.f);
      if (OMODE == 0){
        outf[((size_t)img*Cout + o)*((size_t)Wout*Wout) + (size_t)y*Wout + px] = v;
      } else if (OMODE == 1){
        outb[(size_t)img*outImgStride + ((size_t)(y+1)*pitchOut + px+1)*csOut + coOut + o] = f2b(v);
      } else {
        outb[(size_t)img*outImgStride + ((size_t)y*pitchOut + px)*csOut + coOut + o] = f2b(v);
      }
    }
  }
}

// ---------- combine fuse K-split partials ----------
__global__ __launch_bounds__(256) void fuse_combine(const float* __restrict__ P,
    const float* __restrict__ bias, u16t* __restrict__ outp){
  __shared__ float sb[64];
  if (threadIdx.x < 64) sb[threadIdx.x] = bias[threadIdx.x];
  __syncthreads();
  int idx = blockIdx.x*256 + threadIdx.x;
  int y = idx/IMW, x = idx%IMW;
  u16t* op = outp + ((size_t)(y+1)*PDIM + x+1)*64;
  #pragma unroll
  for (int o8 = 0; o8 < 8; ++o8){
    short8 ov;
    #pragma unroll
    for (int j = 0; j < 8; ++j){
      int o = o8*8 + j;
      float b = sb[o];
      float ps = P[(size_t)(o)*HWF + idx]      + P[(size_t)(128+o)*HWF + idx];
      float pf = P[(size_t)(64+o)*HWF + idx]   + P[(size_t)(192+o)*HWF + idx];
      float v = 0.1f*lrelu(ps + b) + lrelu(pf + b);
      ov[j] = (short)f2b(v);
    }
    *(short8*)(op + o8*8) = ov;
  }
}

// ---------- gating + flow-warp, channels-last bf16 ----------
__global__ __launch_bounds__(256) void gate_nhwc(
    const u16t* __restrict__ fpad, const u16t* __restrict__ pred,
    const float* __restrict__ mv, u16t* __restrict__ spad)
{
  int idx = blockIdx.x*256 + threadIdx.x;
  int t = blockIdx.y;
  int y = idx/IMW, x = idx%IMW;
  size_t pc = ((size_t)(y+1)*PDIM + (x+1))*448;
  const u16t* rp = fpad + pc + 192;
  const u16t* pp = pred + ((size_t)t*HWF + idx)*64;
  u16t* sp = spad + pc + (size_t)t*64;
  const u16t* tp[4]; float tw[4];
  if (t == 0){
    tp[0] = fpad + pc; tw[0] = 1.f;
    tp[1] = tp[2] = tp[3] = fpad + pc; tw[1] = tw[2] = tw[3] = 0.f;
  } else {
    float fx = mv[(((size_t)(t-1)*HWF + idx))*2 + 0];
    float fy = mv[(((size_t)(t-1)*HWF + idx))*2 + 1];
    float ys = (float)y + fy, xs = (float)x + fx;
    float y0f = floorf(ys), x0f = floorf(xs);
    float wy = ys - y0f, wx = xs - x0f;
    int y0 = (int)y0f, x0i = (int)x0f;
    int k = 0;
    #pragma unroll
    for (int dy2 = 0; dy2 < 2; ++dy2)
      #pragma unroll
      for (int dx2 = 0; dx2 < 2; ++dx2){
        int yi = y0+dy2, xi = x0i+dx2;
        float wv = (dy2 ? wy : 1.f-wy)*(dx2 ? wx : 1.f-wx);
        bool ok = (yi >= 0 && yi <= 191 && xi >= 0 && xi <= 191);
        int yc = min(max(yi,0),191), xc = min(max(xi,0),191);
        tp[k] = fpad + ((size_t)(yc+1)*PDIM + xc+1)*448 + (size_t)(t-1)*64;
        tw[k] = ok ? wv : 0.f;
        ++k;
      }
  }
  #pragma unroll
  for (int c8 = 0; c8 < 8; ++c8){
    short8 rv = *(const short8*)(rp + c8*8);
    short8 pv = *(const short8*)(pp + c8*8);
    short8 t0v = *(const short8*)(tp[0] + c8*8);
    short8 t1v = *(const short8*)(tp[1] + c8*8);
    short8 t2v = *(const short8*)(tp[2] + c8*8);
    short8 t3v = *(const short8*)(tp[3] + c8*8);
    short8 ov;
    #pragma unroll
    for (int j = 0; j < 8; ++j){
      float r = b2f((u16t)rv[j]);
      float p = b2f((u16t)pv[j]);
      float a = tw[0]*b2f((u16t)t0v[j]) + tw[1]*b2f((u16t)t1v[j])
              + tw[2]*b2f((u16t)t2v[j]) + tw[3]*b2f((u16t)t3v[j]);
      float sv = a*sigmoidf(a*r) + p*sigmoidf(p*r);
      ov[j] = (short)f2b(sv);
    }
    *(short8*)(sp + c8*8) = ov;
  }
}

// ---------------- convT 4x4 s2 p1 (+relu): parity-decomposed, fp32 in, bf16 NHWC out ----------------
__global__ __launch_bounds__(256) void convT_tile2(
    const float* __restrict__ in, const float* __restrict__ wp,
    const float* __restrict__ bias, u16t* __restrict__ outb,
    int Hin, int tilesX, int pitchOut, int csOut, int coOut)
{
  const int CC = 4;
  __shared__ float sIn[CC][10*11];
  __shared__ float sW[16][CC][4][4];
  const int Win = Hin;
  const int o0 = blockIdx.x*16;
  const int tile = blockIdx.y;
  const int ty0 = (tile/tilesX)*16, tx0 = (tile%tilesX)*16;
  const int tid = threadIdx.x;
  const int py = tid>>4, px = tid&15;
  const int ry = py&1, rx = px&1, par = ry*2 + rx;
  const int lr = py>>1, lc = px>>1;
  const int r0 = ty0>>1, c0 = tx0>>1;
  float acc[16] = {};
  for (int ib = 0; ib < 64; ib += CC){
    for (int i = tid; i < CC*100; i += 256){
      int c = i/100, rem = i%100, r = rem/10, col = rem%10;
      int gy = r0 - 1 + r, gx = c0 - 1 + col;
      float v = 0.f;
      if (gy >= 0 && gy < Hin && gx >= 0 && gx < Win)
        v = in[(size_t)(ib + c)*Hin*Win + gy*Win + gx];
      sIn[c][r*11 + col] = v;
    }
    for (int i = tid; i < 1024; i += 256){
      int ol = i >> 6, rem = i & 63, ci = rem >> 4, p2 = (rem >> 2) & 3, j = rem & 3;
      sW[ol][ci][p2][j] = wp[((size_t)((p2*64 + o0 + ol)*64) + ib + ci)*4 + j];
    }
    __syncthreads();
    #pragma unroll
    for (int ci = 0; ci < CC; ++ci){
      int rb = lr + ry, cb = lc + rx;
      float t00 = sIn[ci][rb*11 + cb],     t01 = sIn[ci][rb*11 + cb + 1];
      float t10 = sIn[ci][(rb+1)*11 + cb], t11 = sIn[ci][(rb+1)*11 + cb + 1];
      #pragma unroll
      for (int ol = 0; ol < 16; ++ol){
        const float* wv = &sW[ol][ci][par][0];
        acc[ol] += t00*wv[0] + t01*wv[1] + t10*wv[2] + t11*wv[3];
      }
    }
    __syncthreads();
  }
  int gy = ty0 + py, gx = tx0 + px;
  u16t* op = outb + ((size_t)(gy+1)*pitchOut + gx+1)*csOut + coOut + o0;
  short8 pa, pb;
  #pragma unroll
  for (int i = 0; i < 8; ++i) pa[i] = (short)f2b(fmaxf(acc[i] + bias[o0+i], 0.f));
  #pragma unroll
  for (int i = 0; i < 8; ++i) pb[i] = (short)f2b(fmaxf(acc[8+i] + bias[o0+8+i], 0.f));
  *(short8*)op = pa;
  *(short8*)(op + 8) = pb;
}

// ---------------- deformable conv ----------------
__global__ __launch_bounds__(256) void deform_sample_k(
    const float* __restrict__ lqs, const float* __restrict__ om,
    float* __restrict__ vbuf)
{
  int idx = blockIdx.x*256 + threadIdx.x;
  int g = blockIdx.y;
  int h = idx / IMW, x = idx % IMW;
  const float* img = lqs + (size_t)g*HWF;
  #pragma unroll
  for (int k = 0; k < 9; ++k){
    int j = g*9 + k;
    float offy = om[(size_t)(j*2 + 0)*HWF + idx];
    float offx = om[(size_t)(j*2 + 1)*HWF + idx];
    float m = sigmoidf(om[(size_t)(126 + j)*HWF + idx]);
    float ys = (float)(h + (k/3) - 1) + offy;
    float xs = (float)(x + (k%3) - 1) + offx;
    vbuf[(size_t)j*HWF + idx] = bilin(img, ys, xs, IMH, IMW) * m;
  }
}

__global__ __launch_bounds__(256) void deform_out_k(
    const float* __restrict__ vbuf, const float* __restrict__ dcw,
    const float* __restrict__ dcb, float* __restrict__ out)
{
  __shared__ float sw[16*63];
  int idx = blockIdx.x*256 + threadIdx.x;
  int o0 = blockIdx.y*16;
  for (int i = threadIdx.x; i < 16*63; i += 256)
    sw[i] = dcw[(size_t)o0*63 + i];
  __syncthreads();
  float v[63];
  #pragma unroll
  for (int j = 0; j < 63; ++j) v[j] = vbuf[(size_t)j*HWF + idx];
  for (int ol = 0; ol < 16; ++ol){
    float acc = dcb[o0 + ol];
    #pragma unroll
    for (int j = 0; j < 63; ++j) acc += v[j]*sw[ol*63 + j];
    out[(size_t)(o0 + ol)*HWF + idx] = fmaxf(acc, 0.f);
  }
}

extern "C" void kernel_launch(void* const* d_in, const int* in_sizes, int n_in,
                              void* d_out, int out_size, void* d_ws, size_t ws_size,
                              hipStream_t stream)
{
  const float* lqs   = (const float*)d_in[0];
  const float* preds = (const float*)d_in[1];
  const float* mv    = (const float*)d_in[2];
  const float* bw1   = (const float*)d_in[3];
  const float* bb1   = (const float*)d_in[4];
  const float* bw2   = (const float*)d_in[5];
  const float* bb2   = (const float*)d_in[6];
  const float* dn1w  = (const float*)d_in[7];
  const float* dn1b  = (const float*)d_in[8];
  const float* dn2w  = (const float*)d_in[9];
  const float* dn2b  = (const float*)d_in[10];
  const float* up1cw = (const float*)d_in[11];
  const float* up1cb = (const float*)d_in[12];
  const float* up1tw = (const float*)d_in[13];
  const float* up1tb = (const float*)d_in[14];
  const float* up2cw = (const float*)d_in[15];
  const float* up2cb = (const float*)d_in[16];
  const float* up2tw = (const float*)d_in[17];
  const float* up2tb = (const float*)d_in[18];
  const float* trcw  = (const float*)d_in[19];
  const float* trcb  = (const float*)d_in[20];
  const float* trtw  = (const float*)d_in[21];
  const float* trtb  = (const float*)d_in[22];
  const float* ffw   = (const float*)d_in[23];
  const float* ffb   = (const float*)d_in[24];
  const float* omw   = (const float*)d_in[25];
  const float* omb   = (const float*)d_in[26];
  const float* dcw   = (const float*)d_in[27];
  const float* dcb   = (const float*)d_in[28];
  float* outp = (float*)d_out;

  char* p = (char*)d_ws;
  const size_t PIMG64 = (size_t)PDIM*PDIM*64;
  u16t* bbpad    = (u16t*)p; p += 14*PIMG64*2;                // conv1 out x14; later spad; later featfpad
  u16t* fpad     = (u16t*)p; p += (size_t)PDIM*PDIM*448*2;    // feat NHWC448; later vbuf (fp32)
  u16t* prednhwc = (u16t*)p; p += (size_t)7*HWF*64*2;         // pred NHWC64; later om (fp32)
  u16t* out0pad  = (u16t*)p; p += (size_t)PDIM*PDIM*64*2;
  u16t* cat1pad  = (u16t*)p; p += (size_t)98*98*128*2;
  u16t* cat2pad  = (u16t*)p; p += (size_t)50*50*128*2;
  float* t0      = (float*)p; p += (size_t)24*24*64*4;
  float* u2      = (float*)p; p += (size_t)48*48*64*4;
  float* u1      = (float*)p; p += (size_t)96*96*64*4;
  u16t* ffwpack  = (u16t*)p; p += 258048*2;
  u16t* c2pack   = (u16t*)p; p += 36864*2;
  u16t* ompack   = (u16t*)p; p += 110592*2;
  u16t* dn1pack  = (u16t*)p; p += 36864*2;
  u16t* dn2pack  = (u16t*)p; p += 36864*2;
  u16t* trcpack  = (u16t*)p; p += 36864*2;
  u16t* up2cpack = (u16t*)p; p += 73728*2;
  u16t* up1cpack = (u16t*)p; p += 73728*2;
  float* wp0     = (float*)p; p += 65536*4;
  float* wp1     = (float*)p; p += 65536*4;
  float* wp2     = (float*)p; p += 65536*4;
  float* fpart   = (float*)p; p += (size_t)256*HWF*4;

  u16t* spad = bbpad;
  u16t* featfpad = bbpad;
  float* om = (float*)prednhwc;
  float* vbuf = (float*)fpad;

  dim3 blk(256);
  // setup: packs + repacks + init padzeros (3 dispatches)
  PkD8 pk = {{ {ffw, ffwpack, 448, 64, 4, 258048}, {bw2, c2pack, 64, 64, 4, 36864},
               {omw, ompack, 64, 189, 12, 110592}, {dn1w, dn1pack, 64, 64, 4, 36864},
               {dn2w, dn2pack, 64, 64, 4, 36864},  {trcw, trcpack, 64, 64, 4, 36864},
               {up2cw, up2cpack, 128, 64, 4, 73728}, {up1cw, up1cpack, 128, 64, 4, 73728} }};
  pack_all<<<dim3(1008,8), blk, 0, stream>>>(pk);
  RpD3 rp3 = {{ {trtw, wp0}, {up2tw, wp1}, {up1tw, wp2} }};
  repack_all<<<dim3(64,3), blk, 0, stream>>>(rp3);
  PzD5 pz = {{ {bbpad, 64, PDIM, 14, PIMG64}, {fpad, 448, PDIM, 1, 0},
               {out0pad, 64, PDIM, 1, 0}, {cat1pad, 128, 98, 1, 0}, {cat2pad, 128, 50, 1, 0} }};
  padzero_all<<<dim3(2704,5), blk, 0, stream>>>(pz);
  // backbone: conv1 x14 imgs, then merged LDS-staged conv2 (img<7 -> fpad, else prednhwc)
  conv1_k<<<dim3(144,14), blk, 0, stream>>>(lqs, preds, bw1, bb1, bbpad);
  cgemm<1,2,12,1><<<dim3(8064,1), blk, 0, stream>>>(bbpad, nullptr, c2pack, bb2,
      nullptr, fpad, prednhwc, 576, PDIM, 64, PIMG64, 2);
  // gate (+warp) -> spad (reuses bbpad region; border zero first)
  padzero2<<<dim3(1352), blk, 0, stream>>>(spad, 448, PDIM);
  gate_nhwc<<<dim3(144,7), blk, 0, stream>>>(fpad, prednhwc, mv, spad);
  // fused dual conv, LDS-staged, K-split x2 -> fp32 partials -> combine
  cgemm<2,7,3,1><<<dim3(576,2), blk, 0, stream>>>(spad, fpad, ffwpack, nullptr,
      fpart, nullptr, nullptr, 576, PDIM, 448, 0, 14);
  fuse_combine<<<dim3(144), blk, 0, stream>>>(fpart, ffb, out0pad);
  // U-Net (gconv3 path)
  gconv3<4,1,2,2,1,1,1><<<dim3(144,1), blk, 0, stream>>>(out0pad, nullptr, dn1pack, dn1b, nullptr, cat1pad,
      64, 96, 6, 144, PDIM, 64, 0, 0, 0, 98, 128, 64, 2, 4);       // out1 -> cat1[64:]
  gconv3<4,1,2,2,1,1,0><<<dim3(36,1), blk, 0, stream>>>(cat1pad, nullptr, dn2pack, dn2b, nullptr, cat2pad,
      64, 48, 3, 36, 98, 128, 64, 0, 0, 50, 128, 64, 2, 4);        // out2 -> cat2[64:]
  gconv3<4,1,2,2,0,1,0><<<dim3(12,1), blk, 0, stream>>>(cat2pad, nullptr, trcpack, trcb, t0, nullptr,
      64, 24, 2, 12, 50, 128, 64, 0, 0, 0, 0, 0, 2, 4);            // t0 (fp32 NCHW)
  convT_tile2<<<dim3(4,9), blk, 0, stream>>>(t0, wp0, trtb, cat2pad, 24, 3, 50, 128, 0);   // t1 -> cat2[:64]
  gconv3<4,1,4,1,0,1,0><<<dim3(36,1), blk, 0, stream>>>(cat2pad, nullptr, up2cpack, up2cb, u2, nullptr,
      64, 48, 3, 36, 50, 128, 0, 0, 0, 0, 0, 0, 4, 4);             // u2 (fp32 NCHW)
  convT_tile2<<<dim3(4,36), blk, 0, stream>>>(u2, wp1, up2tb, cat1pad, 48, 6, 98, 128, 0); // u2t -> cat1[:64]
  gconv3<4,1,4,1,0,1,1><<<dim3(144,1), blk, 0, stream>>>(cat1pad, nullptr, up1cpack, up1cb, u1, nullptr,
      64, 96, 6, 144, 98, 128, 0, 0, 0, 0, 0, 0, 4, 4);            // u1 (fp32 NCHW)
  // final convT -> featfpad (reuses bbpad region, dead after fuse)
  padzero2<<<dim3(194), blk, 0, stream>>>(featfpad, 64, PDIM);
  convT_tile2<<<dim3(4,144), blk, 0, stream>>>(u1, wp2, up1tb, featfpad, 96, 12, PDIM, 64, 0);
  // offsets/masks conv (64 -> 189), NT-split x3 -> om (fp32 NCHW)
  gconv3<4,1,2,1,0,0,1><<<dim3(576,3), blk, 0, stream>>>(featfpad, nullptr, ompack, omb, om, nullptr,
      189, 192, 12, 576, PDIM, 64, 0, 0, 0, 0, 0, 0, 2, 12);
  // deformable conv
  deform_sample_k<<<dim3(144,7), blk, 0, stream>>>(lqs, om, vbuf);
  deform_out_k<<<dim3(144,4), blk, 0, stream>>>(vbuf, dcw, dcb, outp);
}

// Round 7
// 659.540 us; speedup vs baseline: 1.4380x; 1.1497x over previous
//
#include <hip/hip_runtime.h>
#include <math.h>

#define IMH 192
#define IMW 192
#define HWF 36864
#define PDIM 194

typedef unsigned short u16t;
typedef __attribute__((ext_vector_type(8))) short short8;
typedef __attribute__((ext_vector_type(4))) float f32x4;

__device__ __forceinline__ float sigmoidf(float x){ return 1.f/(1.f+expf(-x)); }
__device__ __forceinline__ float lrelu(float x){ return x > 0.f ? x : 0.1f*x; }
__device__ __forceinline__ float b2f(u16t h){ unsigned u = ((unsigned)h)<<16; return __uint_as_float(u); }
__device__ __forceinline__ u16t f2b(float f){
  unsigned u = __float_as_uint(f);
  u += 0x7FFFu + ((u>>16)&1u);
  return (u16t)(u>>16);
}

__device__ __forceinline__ float bilin(const float* __restrict__ img, float ys, float xs, int H, int W){
  float y0f = floorf(ys), x0f = floorf(xs);
  float wy = ys - y0f, wx = xs - x0f;
  int y0 = (int)y0f, x0 = (int)x0f;
  float acc = 0.f;
  #pragma unroll
  for (int dy=0; dy<2; ++dy){
    int yi = y0+dy;
    float wyv = dy ? wy : 1.f-wy;
    if (yi < 0 || yi >= H) continue;
    #pragma unroll
    for (int dx=0; dx<2; ++dx){
      int xi = x0+dx;
      float wxv = dx ? wx : 1.f-wx;
      if (xi < 0 || xi >= W) continue;
      acc += img[yi*W+xi]*(wyv*wxv);
    }
  }
  return acc;
}

// ================= descriptor-driven setup kernels =================
struct PkD { const float* w; u16t* dst; int Cin, Cout, NT, total; };
struct PkD8 { PkD d[8]; };
__global__ __launch_bounds__(256) void pack_all(PkD8 ds){
  PkD d = ds.d[blockIdx.y];
  int id = blockIdx.x*256 + threadIdx.x;
  if (id >= d.total) return;
  int j = id & 7, l = (id>>3) & 63;
  int r = id >> 9;
  int nt = r % d.NT; r /= d.NT;
  int KC = d.Cin >> 5;
  int kc = r % KC; int tap = r / KC;
  int c = kc*32 + ((l>>4)<<3) + j;
  int o = nt*16 + (l&15);
  float v = (o < d.Cout) ? d.w[((size_t)o*d.Cin + c)*9 + tap] : 0.f;
  d.dst[id] = f2b(v);
}

struct RpD { const float* w; float* wp; };
struct RpD3 { RpD d[3]; };
__global__ __launch_bounds__(256) void repack_all(RpD3 ds){
  RpD d = ds.d[blockIdx.y];
  int id = blockIdx.x*256 + threadIdx.x;
  int par = id >> 12, o = (id >> 6) & 63, i = id & 63;
  int ry = par >> 1, rx = par & 1;
  #pragma unroll
  for (int jy = 0; jy < 2; ++jy)
    #pragma unroll
    for (int jx = 0; jx < 2; ++jx){
      int ka = 3 - ry - 2*jy, kb = 3 - rx - 2*jx;
      d.wp[((size_t)((par*64 + o)*64 + i))*4 + jy*2 + jx] = d.w[((size_t)(i*64 + o))*16 + ka*4 + kb];
    }
}

struct PzD { u16t* buf; int C, dim, nimg; size_t stride; };
struct PzD5 { PzD d[5]; };
__global__ __launch_bounds__(256) void padzero_all(PzD5 ds){
  PzD d = ds.d[blockIdx.y];
  int per = (4*d.dim - 4)*d.C;
  long total = (long)per*d.nimg;
  for (long id = (long)blockIdx.x*256 + threadIdx.x; id < total; id += (long)gridDim.x*256){
    int n = (int)(id / per), c2 = (int)(id % per);
    int cell = c2 / d.C, c = c2 % d.C;
    int d2 = d.dim - 1;
    int r, col;
    if (cell < d.dim){ r = 0; col = cell; }
    else if (cell < 2*d.dim){ r = d2; col = cell - d.dim; }
    else if (cell < 3*d.dim - 2){ r = cell - 2*d.dim + 1; col = 0; }
    else { r = cell - (3*d.dim - 2) + 1; col = d2; }
    d.buf[(size_t)n*d.stride + ((size_t)r*d.dim + col)*d.C + c] = 0;
  }
}

__global__ __launch_bounds__(256) void padzero2(u16t* buf, int C, int dim){
  int total = (4*dim - 4)*C;
  for (int id = blockIdx.x*256 + threadIdx.x; id < total; id += gridDim.x*256){
    int cell = id / C, c = id % C;
    int d2 = dim - 1;
    int r, col;
    if (cell < dim){ r = 0; col = cell; }
    else if (cell < 2*dim){ r = d2; col = cell - dim; }
    else if (cell < 3*dim - 2){ r = cell - 2*dim + 1; col = 0; }
    else { r = cell - (3*dim - 2) + 1; col = d2; }
    buf[((size_t)r*dim + col)*C + c] = 0;
  }
}

// ---------- conv1: 1->64ch 3x3, fp32 math, writes padded NHWC bf16; 14 imgs ----------
__global__ __launch_bounds__(256) void conv1_k(const float* __restrict__ lqs, const float* __restrict__ preds,
                                               const float* __restrict__ w,
                                               const float* __restrict__ bias, u16t* __restrict__ outp){
  __shared__ float sw[576];
  __shared__ float sb[64];
  int tid = threadIdx.x;
  for (int i = tid; i < 576; i += 256) sw[i] = w[i];
  if (tid < 64) sb[tid] = bias[tid];
  __syncthreads();
  int idx = blockIdx.x*256 + tid;
  int n = blockIdx.y;
  int y = idx/IMW, x = idx%IMW;
  const float* ip = (n < 7) ? (lqs + (size_t)n*HWF) : (preds + (size_t)(n-7)*HWF);
  float t[9];
  #pragma unroll
  for (int dy = 0; dy < 3; ++dy)
    #pragma unroll
    for (int dx = 0; dx < 3; ++dx){
      int yy = y+dy-1, xx = x+dx-1;
      t[dy*3+dx] = (yy>=0 && yy<IMH && xx>=0 && xx<IMW) ? ip[yy*IMW+xx] : 0.f;
    }
  u16t* op = outp + (size_t)n*(PDIM*PDIM*64) + ((size_t)(y+1)*PDIM + x+1)*64;
  #pragma unroll
  for (int o8 = 0; o8 < 8; ++o8){
    short8 ov;
    #pragma unroll
    for (int j = 0; j < 8; ++j){
      int o = o8*8 + j;
      float acc = sb[o];
      #pragma unroll
      for (int k = 0; k < 9; ++k) acc += t[k]*sw[o*9+k];
      ov[j] = (short)f2b(acc);
    }
    *(short8*)(op + o8*8) = ov;
  }
}

// ========== LDS-staged MFMA implicit-GEMM 3x3 stride-1 conv ==========
// Block = 4 waves = 4-row x 16-px x 64-ch output tile. Per 32-ch K-chunk the block
// stages its 6x18-px input tile in LDS (pixel stride 40 shorts); all 9 taps read LDS.
// Wave shape: 32 px (2 rows) x 32 ch (2 nt).
// OMODE 12: backbone (img<7 -> fpad NHWC448 padded, else prednhwc NHWC64 tight)
// OMODE 4:  fuse direct epilogue 0.1*lrelu(s)+lrelu(f) -> out0pad (bf16 NHWC64 padded)
// OMODE 5:  fp32 NCHW out, blockIdx.y = 64-ch output block (ntB), Cout mask (om conv)
template<int STREAMS, int KC, int OMODE, int NTT, int SWZ>
__global__ __launch_bounds__(256) void cgemm(
    const u16t* __restrict__ A0, const u16t* __restrict__ A1,
    const u16t* __restrict__ Bp, const float* __restrict__ bias,
    float* __restrict__ outf, u16t* __restrict__ outb, u16t* __restrict__ outb2,
    int Cout, int blocksPerImg, int pitchIn, int csIn, size_t aImgStride, int KCtot)
{
  __shared__ u16t sA[STREAMS*108*40];
  int bid = blockIdx.x;
  if (SWZ) bid = (bid & 7)*(gridDim.x >> 3) + (bid >> 3);
  const int tid = threadIdx.x;
  const int wave = tid >> 6, lane = tid & 63;
  const int m = lane & 15, q = lane >> 4;
  const int img = bid / blocksPerImg;
  const int rem = bid - img*blocksPerImg;
  const int yg = rem / 12, xsg = rem % 12;
  const int y0 = yg*4, xs = xsg*16;
  const int rp = wave >> 1, np = wave & 1;
  const int ntB = (OMODE == 5) ? blockIdx.y*4 : 0;
  f32x4 acc[STREAMS][2][2];
  #pragma unroll
  for (int s = 0; s < STREAMS; ++s)
    #pragma unroll
    for (int r = 0; r < 2; ++r)
      #pragma unroll
      for (int n = 0; n < 2; ++n) acc[s][r][n] = (f32x4){0.f,0.f,0.f,0.f};

  #pragma unroll 1
  for (int kc = 0; kc < KC; ++kc){
    if (kc) __syncthreads();
    for (int u = tid; u < STREAMS*216; u += 256){
      int st = u/216, r2 = u%216, p = r2>>1, h = r2&1;
      int rr = p/18, cc = p%18;
      size_t ga = (size_t)img*aImgStride + ((size_t)(y0+rr)*pitchIn + xs+cc)*csIn + kc*32 + h*16;
      const u16t* gp = ((STREAMS==2 && st==1) ? A1 : A0) + ga;
      short8 v0 = *(const short8*)gp;
      short8 v1 = *(const short8*)(gp + 8);
      u16t* lp = &sA[((size_t)(st*108 + p))*40 + h*16];
      *(short8*)lp = v0;
      *(short8*)(lp+8) = v1;
    }
    __syncthreads();
    #pragma unroll
    for (int tap = 0; tap < 9; ++tap){
      const int dy = tap/3, dx = tap%3;
      short8 af[STREAMS][2];
      #pragma unroll
      for (int st = 0; st < STREAMS; ++st)
        #pragma unroll
        for (int r = 0; r < 2; ++r)
          af[st][r] = *(const short8*)&sA[((size_t)(st*108 + (2*rp + r + dy)*18 + dx + m))*40 + q*8];
      const u16t* bp = Bp + ((size_t)(tap*KCtot + kc)*NTT + ntB + np*2)*512 + lane*8;
      short8 b0 = *(const short8*)bp;
      short8 b1 = *(const short8*)(bp + 512);
      #pragma unroll
      for (int st = 0; st < STREAMS; ++st)
        #pragma unroll
        for (int r = 0; r < 2; ++r){
          acc[st][r][0] = __builtin_amdgcn_mfma_f32_16x16x32_bf16(af[st][r], b0, acc[st][r][0], 0, 0, 0);
          acc[st][r][1] = __builtin_amdgcn_mfma_f32_16x16x32_bf16(af[st][r], b1, acc[st][r][1], 0, 0, 0);
        }
    }
  }
  // epilogue. C/D: col=lane&15 (out ch), row=q*4+reg (pixel in strip)
  const int px0 = q*4;
  #pragma unroll
  for (int r = 0; r < 2; ++r){
    int yout = y0 + 2*rp + r;
    #pragma unroll
    for (int n = 0; n < 2; ++n){
      int oL = (np*2 + n)*16 + m;
      if (OMODE == 4){
        float bv = bias[oL];
        #pragma unroll
        for (int g = 0; g < 4; ++g){
          int px = xs + px0 + g;
          float v = 0.1f*lrelu(acc[0][r][n][g] + bv) + lrelu(acc[1][r][n][g] + bv);
          outb[((size_t)(yout+1)*PDIM + px+1)*64 + oL] = f2b(v);
        }
      } else if (OMODE == 5){
        int o = ntB*16 + oL;
        if (o < Cout){
          float bv = bias[o];
          #pragma unroll
          for (int g = 0; g < 4; ++g){
            int px = xs + px0 + g;
            outf[(size_t)o*HWF + (size_t)yout*IMW + px] = acc[0][r][n][g] + bv;
          }
        }
      } else {
        float bv = bias[oL];
        #pragma unroll
        for (int g = 0; g < 4; ++g){
          int px = xs + px0 + g;
          float v = acc[0][r][n][g] + bv;
          if (img < 7)
            outb[((size_t)(yout+1)*PDIM + px+1)*448 + (size_t)img*64 + oL] = f2b(v);
          else
            outb2[(size_t)(img-7)*((size_t)HWF*64) + ((size_t)yout*IMW + px)*64 + oL] = f2b(v);
        }
      }
    }
  }
}

// ---------- no-LDS MFMA implicit-GEMM (U-Net smalls) ----------
template<int NT, int STREAMS, int KC, int STRIDE, int OMODE, int ACT, int SWZ>
__global__ __launch_bounds__(256) void gconv3(
    const u16t* __restrict__ A0, const u16t* __restrict__ A1,
    const u16t* __restrict__ Bp, const float* __restrict__ bias,
    float* __restrict__ outf, u16t* __restrict__ outb,
    int Cout, int Wout, int strips, int blocksPerImg,
    int pitchIn, int csIn, int coIn, size_t aImgStride,
    size_t outImgStride, int pitchOut, int csOut, int coOut,
    int KCtot, int NTtot)
{
  int bid = blockIdx.x;
  if (SWZ) bid = (bid & 7)*(gridDim.x >> 3) + (bid >> 3);
  const int wave = threadIdx.x >> 6;
  const int lane = threadIdx.x & 63;
  const int img = bid / blocksPerImg;
  const int sid = (bid - img*blocksPerImg)*4 + wave;
  const int y = sid / strips, xs = (sid % strips) * 16;
  const int m = lane & 15, q = lane >> 4;
  const int ntOff = blockIdx.y*NT;
  f32x4 acc[NT];
  #pragma unroll
  for (int nt = 0; nt < NT; ++nt) acc[nt] = (f32x4){0.f,0.f,0.f,0.f};

  for (int tap = 0; tap < 9; ++tap){
    int dy = tap/3, dx = tap%3;
    int row = STRIDE*y + dy;
    int col = (STRIDE == 1) ? (xs + m + dx) : (2*(xs + m) + dx);
    size_t abase = (size_t)img*aImgStride + ((size_t)row*pitchIn + col)*csIn + coIn + q*8;
    const u16t* ap0 = A0 + abase;
    const u16t* bp = Bp + ((size_t)(tap*KCtot)*NTtot + ntOff)*512 + lane*8;
    #pragma unroll
    for (int kc = 0; kc < KC; ++kc){
      short8 av0 = *(const short8*)(ap0 + kc*32);
      #pragma unroll
      for (int nt = 0; nt < NT; ++nt){
        short8 bv = *(const short8*)(bp + (size_t)(kc*NTtot + nt)*512);
        acc[nt] = __builtin_amdgcn_mfma_f32_16x16x32_bf16(av0, bv, acc[nt], 0, 0, 0);
      }
    }
  }
  const int prow0 = q*4;
  #pragma unroll
  for (int nt = 0; nt < NT; ++nt){
    int o = (ntOff + nt)*16 + m;
    if (o >= Cout) continue;
    float bv = bias[o];
    #pragma unroll
    for (int r = 0; r < 4; ++r){
      int px = xs + prow0 + r;
      if (px >= Wout) continue;
      float v = acc[nt][r] + bv;
      if (ACT) v = fmaxf(v, 0.f);
      if (OMODE == 0){
        outf[((size_t)img*Cout + o)*((size_t)Wout*Wout) + (size_t)y*Wout + px] = v;
      } else if (OMODE == 1){
        outb[(size_t)img*outImgStride + ((size_t)(y+1)*pitchOut + px+1)*csOut + coOut + o] = f2b(v);
      } else {
        outb[(size_t)img*outImgStride + ((size_t)y*pitchOut + px)*csOut + coOut + o] = f2b(v);
      }
    }
  }
}

// ---------- gating + flow-warp, channels-last bf16, XCD-banded ----------
// grid 1008: xcd = bid&7 owns a 24-row band for ALL 7 t (L2 locality).
__global__ __launch_bounds__(256) void gate_nhwc(
    const u16t* __restrict__ fpad, const u16t* __restrict__ pred,
    const float* __restrict__ mv, u16t* __restrict__ spad)
{
  int bid = blockIdx.x;
  int xcd = bid & 7;
  int k = bid >> 3;          // 0..125
  int t = k % 7;
  int lb = k / 7;            // 0..17
  int idx = (xcd*18 + lb)*256 + threadIdx.x;
  int y = idx/IMW, x = idx%IMW;
  size_t pc = ((size_t)(y+1)*PDIM + (x+1))*448;
  const u16t* rp = fpad + pc + 192;
  const u16t* pp = pred + ((size_t)t*HWF + idx)*64;
  u16t* sp = spad + pc + (size_t)t*64;
  const u16t* tp[4]; float tw[4];
  if (t == 0){
    tp[0] = fpad + pc; tw[0] = 1.f;
    tp[1] = tp[2] = tp[3] = fpad + pc; tw[1] = tw[2] = tw[3] = 0.f;
  } else {
    float fx = mv[(((size_t)(t-1)*HWF + idx))*2 + 0];
    float fy = mv[(((size_t)(t-1)*HWF + idx))*2 + 1];
    float ys = (float)y + fy, xs = (float)x + fx;
    float y0f = floorf(ys), x0f = floorf(xs);
    float wy = ys - y0f, wx = xs - x0f;
    int y0 = (int)y0f, x0i = (int)x0f;
    int kk = 0;
    #pragma unroll
    for (int dy2 = 0; dy2 < 2; ++dy2)
      #pragma unroll
      for (int dx2 = 0; dx2 < 2; ++dx2){
        int yi = y0+dy2, xi = x0i+dx2;
        float wv = (dy2 ? wy : 1.f-wy)*(dx2 ? wx : 1.f-wx);
        bool ok = (yi >= 0 && yi <= 191 && xi >= 0 && xi <= 191);
        int yc = min(max(yi,0),191), xc = min(max(xi,0),191);
        tp[kk] = fpad + ((size_t)(yc+1)*PDIM + xc+1)*448 + (size_t)(t-1)*64;
        tw[kk] = ok ? wv : 0.f;
        ++kk;
      }
  }
  #pragma unroll
  for (int c8 = 0; c8 < 8; ++c8){
    short8 rv = *(const short8*)(rp + c8*8);
    short8 pv = *(const short8*)(pp + c8*8);
    short8 t0v = *(const short8*)(tp[0] + c8*8);
    short8 t1v = *(const short8*)(tp[1] + c8*8);
    short8 t2v = *(const short8*)(tp[2] + c8*8);
    short8 t3v = *(const short8*)(tp[3] + c8*8);
    short8 ov;
    #pragma unroll
    for (int j = 0; j < 8; ++j){
      float r = b2f((u16t)rv[j]);
      float p = b2f((u16t)pv[j]);
      float a = tw[0]*b2f((u16t)t0v[j]) + tw[1]*b2f((u16t)t1v[j])
              + tw[2]*b2f((u16t)t2v[j]) + tw[3]*b2f((u16t)t3v[j]);
      float sv = a*sigmoidf(a*r) + p*sigmoidf(p*r);
      ov[j] = (short)f2b(sv);
    }
    *(short8*)(sp + c8*8) = ov;
  }
}

// ---------------- convT 4x4 s2 p1 (+relu): parity-decomposed, fp32 in, bf16 NHWC out ----------------
__global__ __launch_bounds__(256) void convT_tile2(
    const float* __restrict__ in, const float* __restrict__ wp,
    const float* __restrict__ bias, u16t* __restrict__ outb,
    int Hin, int tilesX, int pitchOut, int csOut, int coOut)
{
  const int CC = 4;
  __shared__ float sIn[CC][10*11];
  __shared__ float sW[16][CC][4][4];
  const int Win = Hin;
  const int o0 = blockIdx.x*16;
  const int tile = blockIdx.y;
  const int ty0 = (tile/tilesX)*16, tx0 = (tile%tilesX)*16;
  const int tid = threadIdx.x;
  const int py = tid>>4, px = tid&15;
  const int ry = py&1, rx = px&1, par = ry*2 + rx;
  const int lr = py>>1, lc = px>>1;
  const int r0 = ty0>>1, c0 = tx0>>1;
  float acc[16] = {};
  for (int ib = 0; ib < 64; ib += CC){
    for (int i = tid; i < CC*100; i += 256){
      int c = i/100, rem = i%100, r = rem/10, col = rem%10;
      int gy = r0 - 1 + r, gx = c0 - 1 + col;
      float v = 0.f;
      if (gy >= 0 && gy < Hin && gx >= 0 && gx < Win)
        v = in[(size_t)(ib + c)*Hin*Win + gy*Win + gx];
      sIn[c][r*11 + col] = v;
    }
    for (int i = tid; i < 1024; i += 256){
      int ol = i >> 6, rem = i & 63, ci = rem >> 4, p2 = (rem >> 2) & 3, j = rem & 3;
      sW[ol][ci][p2][j] = wp[((size_t)((p2*64 + o0 + ol)*64) + ib + ci)*4 + j];
    }
    __syncthreads();
    #pragma unroll
    for (int ci = 0; ci < CC; ++ci){
      int rb = lr + ry, cb = lc + rx;
      float t00 = sIn[ci][rb*11 + cb],     t01 = sIn[ci][rb*11 + cb + 1];
      float t10 = sIn[ci][(rb+1)*11 + cb], t11 = sIn[ci][(rb+1)*11 + cb + 1];
      #pragma unroll
      for (int ol = 0; ol < 16; ++ol){
        const float* wv = &sW[ol][ci][par][0];
        acc[ol] += t00*wv[0] + t01*wv[1] + t10*wv[2] + t11*wv[3];
      }
    }
    __syncthreads();
  }
  int gy = ty0 + py, gx = tx0 + px;
  u16t* op = outb + ((size_t)(gy+1)*pitchOut + gx+1)*csOut + coOut + o0;
  short8 pa, pb;
  #pragma unroll
  for (int i = 0; i < 8; ++i) pa[i] = (short)f2b(fmaxf(acc[i] + bias[o0+i], 0.f));
  #pragma unroll
  for (int i = 0; i < 8; ++i) pb[i] = (short)f2b(fmaxf(acc[8+i] + bias[o0+8+i], 0.f));
  *(short8*)op = pa;
  *(short8*)(op + 8) = pb;
}

// ---------------- deformable conv ----------------
__global__ __launch_bounds__(256) void deform_sample_k(
    const float* __restrict__ lqs, const float* __restrict__ om,
    float* __restrict__ vbuf)
{
  int idx = blockIdx.x*256 + threadIdx.x;
  int g = blockIdx.y;
  int h = idx / IMW, x = idx % IMW;
  const float* img = lqs + (size_t)g*HWF;
  #pragma unroll
  for (int k = 0; k < 9; ++k){
    int j = g*9 + k;
    float offy = om[(size_t)(j*2 + 0)*HWF + idx];
    float offx = om[(size_t)(j*2 + 1)*HWF + idx];
    float m = sigmoidf(om[(size_t)(126 + j)*HWF + idx]);
    float ys = (float)(h + (k/3) - 1) + offy;
    float xs = (float)(x + (k%3) - 1) + offx;
    vbuf[(size_t)j*HWF + idx] = bilin(img, ys, xs, IMH, IMW) * m;
  }
}

__global__ __launch_bounds__(256) void deform_out_k(
    const float* __restrict__ vbuf, const float* __restrict__ dcw,
    const float* __restrict__ dcb, float* __restrict__ out)
{
  __shared__ float sw[16*63];
  int idx = blockIdx.x*256 + threadIdx.x;
  int o0 = blockIdx.y*16;
  for (int i = threadIdx.x; i < 16*63; i += 256)
    sw[i] = dcw[(size_t)o0*63 + i];
  __syncthreads();
  float v[63];
  #pragma unroll
  for (int j = 0; j < 63; ++j) v[j] = vbuf[(size_t)j*HWF + idx];
  for (int ol = 0; ol < 16; ++ol){
    float acc = dcb[o0 + ol];
    #pragma unroll
    for (int j = 0; j < 63; ++j) acc += v[j]*sw[ol*63 + j];
    out[(size_t)(o0 + ol)*HWF + idx] = fmaxf(acc, 0.f);
  }
}

extern "C" void kernel_launch(void* const* d_in, const int* in_sizes, int n_in,
                              void* d_out, int out_size, void* d_ws, size_t ws_size,
                              hipStream_t stream)
{
  const float* lqs   = (const float*)d_in[0];
  const float* preds = (const float*)d_in[1];
  const float* mv    = (const float*)d_in[2];
  const float* bw1   = (const float*)d_in[3];
  const float* bb1   = (const float*)d_in[4];
  const float* bw2   = (const float*)d_in[5];
  const float* bb2   = (const float*)d_in[6];
  const float* dn1w  = (const float*)d_in[7];
  const float* dn1b  = (const float*)d_in[8];
  const float* dn2w  = (const float*)d_in[9];
  const float* dn2b  = (const float*)d_in[10];
  const float* up1cw = (const float*)d_in[11];
  const float* up1cb = (const float*)d_in[12];
  const float* up1tw = (const float*)d_in[13];
  const float* up1tb = (const float*)d_in[14];
  const float* up2cw = (const float*)d_in[15];
  const float* up2cb = (const float*)d_in[16];
  const float* up2tw = (const float*)d_in[17];
  const float* up2tb = (const float*)d_in[18];
  const float* trcw  = (const float*)d_in[19];
  const float* trcb  = (const float*)d_in[20];
  const float* trtw  = (const float*)d_in[21];
  const float* trtb  = (const float*)d_in[22];
  const float* ffw   = (const float*)d_in[23];
  const float* ffb   = (const float*)d_in[24];
  const float* omw   = (const float*)d_in[25];
  const float* omb   = (const float*)d_in[26];
  const float* dcw   = (const float*)d_in[27];
  const float* dcb   = (const float*)d_in[28];
  float* outp = (float*)d_out;

  char* p = (char*)d_ws;
  const size_t PIMG64 = (size_t)PDIM*PDIM*64;
  u16t* bbpad    = (u16t*)p; p += 14*PIMG64*2;                // conv1 out x14; later spad; later featfpad
  u16t* fpad     = (u16t*)p; p += (size_t)PDIM*PDIM*448*2;    // feat NHWC448; later vbuf (fp32)
  u16t* prednhwc = (u16t*)p; p += (size_t)7*HWF*64*2;         // pred NHWC64; later om (fp32)
  u16t* out0pad  = (u16t*)p; p += (size_t)PDIM*PDIM*64*2;
  u16t* cat1pad  = (u16t*)p; p += (size_t)98*98*128*2;
  u16t* cat2pad  = (u16t*)p; p += (size_t)50*50*128*2;
  float* t0      = (float*)p; p += (size_t)24*24*64*4;
  float* u2      = (float*)p; p += (size_t)48*48*64*4;
  float* u1      = (float*)p; p += (size_t)96*96*64*4;
  u16t* ffwpack  = (u16t*)p; p += 258048*2;
  u16t* c2pack   = (u16t*)p; p += 36864*2;
  u16t* ompack   = (u16t*)p; p += 110592*2;
  u16t* dn1pack  = (u16t*)p; p += 36864*2;
  u16t* dn2pack  = (u16t*)p; p += 36864*2;
  u16t* trcpack  = (u16t*)p; p += 36864*2;
  u16t* up2cpack = (u16t*)p; p += 73728*2;
  u16t* up1cpack = (u16t*)p; p += 73728*2;
  float* wp0     = (float*)p; p += 65536*4;
  float* wp1     = (float*)p; p += 65536*4;
  float* wp2     = (float*)p; p += 65536*4;

  u16t* spad = bbpad;
  u16t* featfpad = bbpad;
  float* om = (float*)prednhwc;
  float* vbuf = (float*)fpad;

  dim3 blk(256);
  // setup
  PkD8 pk = {{ {ffw, ffwpack, 448, 64, 4, 258048}, {bw2, c2pack, 64, 64, 4, 36864},
               {omw, ompack, 64, 189, 12, 110592}, {dn1w, dn1pack, 64, 64, 4, 36864},
               {dn2w, dn2pack, 64, 64, 4, 36864},  {trcw, trcpack, 64, 64, 4, 36864},
               {up2cw, up2cpack, 128, 64, 4, 73728}, {up1cw, up1cpack, 128, 64, 4, 73728} }};
  pack_all<<<dim3(1008,8), blk, 0, stream>>>(pk);
  RpD3 rp3 = {{ {trtw, wp0}, {up2tw, wp1}, {up1tw, wp2} }};
  repack_all<<<dim3(64,3), blk, 0, stream>>>(rp3);
  PzD5 pz = {{ {bbpad, 64, PDIM, 14, PIMG64}, {fpad, 448, PDIM, 1, 0},
               {out0pad, 64, PDIM, 1, 0}, {cat1pad, 128, 98, 1, 0}, {cat2pad, 128, 50, 1, 0} }};
  padzero_all<<<dim3(2704,5), blk, 0, stream>>>(pz);
  // backbone: conv1 x14, then merged LDS-staged conv2
  conv1_k<<<dim3(144,14), blk, 0, stream>>>(lqs, preds, bw1, bb1, bbpad);
  cgemm<1,2,12,4,1><<<dim3(8064,1), blk, 0, stream>>>(bbpad, nullptr, c2pack, bb2,
      nullptr, fpad, prednhwc, 64, 576, PDIM, 64, PIMG64, 2);
  // gate (+warp) -> spad (XCD-banded; border zero first)
  padzero2<<<dim3(1352), blk, 0, stream>>>(spad, 448, PDIM);
  gate_nhwc<<<dim3(1008), blk, 0, stream>>>(fpad, prednhwc, mv, spad);
  // fused dual conv: single-pass LDS-staged, direct epilogue -> out0pad
  cgemm<2,14,4,4,1><<<dim3(576,1), blk, 0, stream>>>(spad, fpad, ffwpack, ffb,
      nullptr, out0pad, nullptr, 64, 576, PDIM, 448, 0, 14);
  // U-Net
  gconv3<4,1,2,2,1,1,1><<<dim3(144,1), blk, 0, stream>>>(out0pad, nullptr, dn1pack, dn1b, nullptr, cat1pad,
      64, 96, 6, 144, PDIM, 64, 0, 0, 0, 98, 128, 64, 2, 4);       // out1 -> cat1[64:]
  gconv3<4,1,2,2,1,1,0><<<dim3(36,1), blk, 0, stream>>>(cat1pad, nullptr, dn2pack, dn2b, nullptr, cat2pad,
      64, 48, 3, 36, 98, 128, 64, 0, 0, 50, 128, 64, 2, 4);        // out2 -> cat2[64:]
  gconv3<4,1,2,2,0,1,0><<<dim3(12,1), blk, 0, stream>>>(cat2pad, nullptr, trcpack, trcb, t0, nullptr,
      64, 24, 2, 12, 50, 128, 64, 0, 0, 0, 0, 0, 2, 4);            // t0 (fp32 NCHW)
  convT_tile2<<<dim3(4,9), blk, 0, stream>>>(t0, wp0, trtb, cat2pad, 24, 3, 50, 128, 0);   // t1 -> cat2[:64]
  gconv3<4,1,4,1,0,1,0><<<dim3(36,1), blk, 0, stream>>>(cat2pad, nullptr, up2cpack, up2cb, u2, nullptr,
      64, 48, 3, 36, 50, 128, 0, 0, 0, 0, 0, 0, 4, 4);             // u2 (fp32 NCHW)
  convT_tile2<<<dim3(4,36), blk, 0, stream>>>(u2, wp1, up2tb, cat1pad, 48, 6, 98, 128, 0); // u2t -> cat1[:64]
  gconv3<4,1,4,1,0,1,1><<<dim3(144,1), blk, 0, stream>>>(cat1pad, nullptr, up1cpack, up1cb, u1, nullptr,
      64, 96, 6, 144, 98, 128, 0, 0, 0, 0, 0, 0, 4, 4);            // u1 (fp32 NCHW)
  // final convT -> featfpad
  padzero2<<<dim3(194), blk, 0, stream>>>(featfpad, 64, PDIM);
  convT_tile2<<<dim3(4,144), blk, 0, stream>>>(u1, wp2, up1tb, featfpad, 96, 12, PDIM, 64, 0);
  // offsets/masks conv (64 -> 189): LDS-staged, blockIdx.y = 64-ch out block
  cgemm<1,2,5,12,1><<<dim3(576,3), blk, 0, stream>>>(featfpad, nullptr, ompack, omb,
      om, nullptr, nullptr, 189, 576, PDIM, 64, 0, 2);
  // deformable conv
  deform_sample_k<<<dim3(144,7), blk, 0, stream>>>(lqs, om, vbuf);
  deform_out_k<<<dim3(144,4), blk, 0, stream>>>(vbuf, dcw, dcb, outp);
}

// Round 8
// 604.730 us; speedup vs baseline: 1.5684x; 1.0906x over previous
//
#include <hip/hip_runtime.h>
#include <math.h>

#define IMH 192
#define IMW 192
#define HWF 36864
#define PDIM 194

typedef unsigned short u16t;
typedef __attribute__((ext_vector_type(8))) short short8;
typedef __attribute__((ext_vector_type(4))) float f32x4;

__device__ __forceinline__ float sigmoidf(float x){ return 1.f/(1.f+expf(-x)); }
__device__ __forceinline__ float lrelu(float x){ return x > 0.f ? x : 0.1f*x; }
__device__ __forceinline__ float b2f(u16t h){ unsigned u = ((unsigned)h)<<16; return __uint_as_float(u); }
__device__ __forceinline__ u16t f2b(float f){
  unsigned u = __float_as_uint(f);
  u += 0x7FFFu + ((u>>16)&1u);
  return (u16t)(u>>16);
}

__device__ __forceinline__ float bilin(const float* __restrict__ img, float ys, float xs, int H, int W){
  float y0f = floorf(ys), x0f = floorf(xs);
  float wy = ys - y0f, wx = xs - x0f;
  int y0 = (int)y0f, x0 = (int)x0f;
  float acc = 0.f;
  #pragma unroll
  for (int dy=0; dy<2; ++dy){
    int yi = y0+dy;
    float wyv = dy ? wy : 1.f-wy;
    if (yi < 0 || yi >= H) continue;
    #pragma unroll
    for (int dx=0; dx<2; ++dx){
      int xi = x0+dx;
      float wxv = dx ? wx : 1.f-wx;
      if (xi < 0 || xi >= W) continue;
      acc += img[yi*W+xi]*(wyv*wxv);
    }
  }
  return acc;
}

// ================= descriptor-driven setup kernels =================
struct PkD { const float* w; u16t* dst; int Cin, Cout, NT, total; };
struct PkD8 { PkD d[8]; };
__global__ __launch_bounds__(256) void pack_all(PkD8 ds){
  PkD d = ds.d[blockIdx.y];
  int id = blockIdx.x*256 + threadIdx.x;
  if (id >= d.total) return;
  int j = id & 7, l = (id>>3) & 63;
  int r = id >> 9;
  int nt = r % d.NT; r /= d.NT;
  int KC = d.Cin >> 5;
  int kc = r % KC; int tap = r / KC;
  int c = kc*32 + ((l>>4)<<3) + j;
  int o = nt*16 + (l&15);
  float v = (o < d.Cout) ? d.w[((size_t)o*d.Cin + c)*9 + tap] : 0.f;
  d.dst[id] = f2b(v);
}

struct RpD { const float* w; float* wp; };
struct RpD3 { RpD d[3]; };
__global__ __launch_bounds__(256) void repack_all(RpD3 ds){
  RpD d = ds.d[blockIdx.y];
  int id = blockIdx.x*256 + threadIdx.x;
  int par = id >> 12, o = (id >> 6) & 63, i = id & 63;
  int ry = par >> 1, rx = par & 1;
  #pragma unroll
  for (int jy = 0; jy < 2; ++jy)
    #pragma unroll
    for (int jx = 0; jx < 2; ++jx){
      int ka = 3 - ry - 2*jy, kb = 3 - rx - 2*jx;
      d.wp[((size_t)((par*64 + o)*64 + i))*4 + jy*2 + jx] = d.w[((size_t)(i*64 + o))*16 + ka*4 + kb];
    }
}

struct PzD { u16t* buf; int C, dim, nimg; size_t stride; };
struct PzD5 { PzD d[5]; };
__global__ __launch_bounds__(256) void padzero_all(PzD5 ds){
  PzD d = ds.d[blockIdx.y];
  int per = (4*d.dim - 4)*d.C;
  long total = (long)per*d.nimg;
  for (long id = (long)blockIdx.x*256 + threadIdx.x; id < total; id += (long)gridDim.x*256){
    int n = (int)(id / per), c2 = (int)(id % per);
    int cell = c2 / d.C, c = c2 % d.C;
    int d2 = d.dim - 1;
    int r, col;
    if (cell < d.dim){ r = 0; col = cell; }
    else if (cell < 2*d.dim){ r = d2; col = cell - d.dim; }
    else if (cell < 3*d.dim - 2){ r = cell - 2*d.dim + 1; col = 0; }
    else { r = cell - (3*d.dim - 2) + 1; col = d2; }
    d.buf[(size_t)n*d.stride + ((size_t)r*d.dim + col)*d.C + c] = 0;
  }
}

__global__ __launch_bounds__(256) void padzero2(u16t* buf, int C, int dim){
  int total = (4*dim - 4)*C;
  for (int id = blockIdx.x*256 + threadIdx.x; id < total; id += gridDim.x*256){
    int cell = id / C, c = id % C;
    int d2 = dim - 1;
    int r, col;
    if (cell < dim){ r = 0; col = cell; }
    else if (cell < 2*dim){ r = d2; col = cell - dim; }
    else if (cell < 3*dim - 2){ r = cell - 2*dim + 1; col = 0; }
    else { r = cell - (3*dim - 2) + 1; col = d2; }
    buf[((size_t)r*dim + col)*C + c] = 0;
  }
}

// ========== fused backbone: conv1 (1->64, fp32) + conv2 (64->64, MFMA), no HBM intermediate ==========
// Block = 4-row x 16-px x 64-ch conv2-output tile. Stages 8x20 raw input fp32 in LDS,
// computes the 6x18x64 feat1 tile (bf16, f2b-rounded, border-zeroed) into LDS, then
// runs both 32-ch MFMA K-chunks from LDS. img<7 -> fpad NHWC448 padded, else prednhwc tight.
__global__ __launch_bounds__(256) void bbfused(
    const float* __restrict__ lqs, const float* __restrict__ preds,
    const float* __restrict__ w1, const float* __restrict__ b1,
    const u16t* __restrict__ Bp, const float* __restrict__ b2,
    u16t* __restrict__ fpad, u16t* __restrict__ prednhwc)
{
  __shared__ float sIn1[8][20];
  __shared__ float sw1[576];
  __shared__ float sb1[64];
  __shared__ u16t sA[108*68];
  int bid = blockIdx.x;
  bid = (bid & 7)*(gridDim.x >> 3) + (bid >> 3);       // XCD banding (8064 % 8 == 0)
  const int tid = threadIdx.x;
  const int img = bid / 576;
  const int rem = bid - img*576;
  const int y0 = (rem/12)*4, xs = (rem%12)*16;
  // conv1 weights
  for (int i = tid; i < 576; i += 256) sw1[i] = w1[i];
  if (tid < 64) sb1[tid] = b1[tid];
  // raw input tile 8x20 (image rows y0-2..y0+5, cols xs-2..xs+17), zero outside
  const float* ip = (img < 7) ? (lqs + (size_t)img*HWF) : (preds + (size_t)(img-7)*HWF);
  for (int u = tid; u < 160; u += 256){
    int lr = u/20, lc = u%20;
    int iy = y0 - 2 + lr, ix = xs - 2 + lc;
    sIn1[lr][lc] = (iy >= 0 && iy < IMH && ix >= 0 && ix < IMW) ? ip[iy*IMW + ix] : 0.f;
  }
  __syncthreads();
  // feat1 tile: 108 px x 64 ch -> sA (2 threads per px, 32 ch each)
  for (int u = tid; u < 216; u += 256){
    int px = u >> 1, half = u & 1;
    int rr = px/18, cc = px%18;
    int pr = y0 + rr, pc = xs + cc;
    bool border = (pr == 0) | (pr == 193) | (pc == 0) | (pc == 193);
    float t[9];
    #pragma unroll
    for (int dy = 0; dy < 3; ++dy)
      #pragma unroll
      for (int dx = 0; dx < 3; ++dx) t[dy*3+dx] = sIn1[rr+dy][cc+dx];
    #pragma unroll
    for (int o8 = 0; o8 < 4; ++o8){
      int ob = half*32 + o8*8;
      short8 ov;
      #pragma unroll
      for (int j = 0; j < 8; ++j){
        int o = ob + j;
        float acc = sb1[o];
        #pragma unroll
        for (int k = 0; k < 9; ++k) acc += t[k]*sw1[o*9+k];
        ov[j] = (short)(border ? (u16t)0 : f2b(acc));
      }
      *(short8*)&sA[(size_t)px*68 + ob] = ov;
    }
  }
  __syncthreads();
  // MFMA from LDS (both kc chunks, no restage)
  const int wave = tid >> 6, lane = tid & 63;
  const int m = lane & 15, q = lane >> 4;
  const int rp = wave >> 1, np = wave & 1;
  f32x4 acc[2][2];
  #pragma unroll
  for (int r = 0; r < 2; ++r)
    #pragma unroll
    for (int n = 0; n < 2; ++n) acc[r][n] = (f32x4){0.f,0.f,0.f,0.f};
  #pragma unroll
  for (int kc = 0; kc < 2; ++kc){
    #pragma unroll
    for (int tap = 0; tap < 9; ++tap){
      const int dy = tap/3, dx = tap%3;
      short8 af[2];
      #pragma unroll
      for (int r = 0; r < 2; ++r)
        af[r] = *(const short8*)&sA[(size_t)((2*rp + r + dy)*18 + dx + m)*68 + kc*32 + q*8];
      const u16t* bp = Bp + ((size_t)(tap*2 + kc)*4 + np*2)*512 + lane*8;
      short8 b0 = *(const short8*)bp;
      short8 b1v = *(const short8*)(bp + 512);
      #pragma unroll
      for (int r = 0; r < 2; ++r){
        acc[r][0] = __builtin_amdgcn_mfma_f32_16x16x32_bf16(af[r], b0, acc[r][0], 0, 0, 0);
        acc[r][1] = __builtin_amdgcn_mfma_f32_16x16x32_bf16(af[r], b1v, acc[r][1], 0, 0, 0);
      }
    }
  }
  const int px0 = q*4;
  #pragma unroll
  for (int r = 0; r < 2; ++r){
    int yout = y0 + 2*rp + r;
    #pragma unroll
    for (int n = 0; n < 2; ++n){
      int oL = (np*2 + n)*16 + m;
      float bv = b2[oL];
      #pragma unroll
      for (int g = 0; g < 4; ++g){
        int px = xs + px0 + g;
        float v = acc[r][n][g] + bv;
        if (img < 7)
          fpad[((size_t)(yout+1)*PDIM + px+1)*448 + (size_t)img*64 + oL] = f2b(v);
        else
          prednhwc[(size_t)(img-7)*((size_t)HWF*64) + ((size_t)yout*IMW + px)*64 + oL] = f2b(v);
      }
    }
  }
}

// ========== LDS-staged MFMA implicit-GEMM 3x3 stride-1 conv ==========
// OMODE 4: fuse epilogue 0.1*lrelu(s)+lrelu(f) -> out0pad; OMODE 5: fp32 NCHW, blockIdx.y=o-block
template<int STREAMS, int KC, int OMODE, int NTT, int SWZ>
__global__ __launch_bounds__(256) void cgemm(
    const u16t* __restrict__ A0, const u16t* __restrict__ A1,
    const u16t* __restrict__ Bp, const float* __restrict__ bias,
    float* __restrict__ outf, u16t* __restrict__ outb, u16t* __restrict__ outb2,
    int Cout, int blocksPerImg, int pitchIn, int csIn, size_t aImgStride, int KCtot)
{
  __shared__ u16t sA[STREAMS*108*40];
  int bid = blockIdx.x;
  if (SWZ) bid = (bid & 7)*(gridDim.x >> 3) + (bid >> 3);
  const int tid = threadIdx.x;
  const int wave = tid >> 6, lane = tid & 63;
  const int m = lane & 15, q = lane >> 4;
  const int img = bid / blocksPerImg;
  const int rem = bid - img*blocksPerImg;
  const int y0 = (rem/12)*4, xs = (rem%12)*16;
  const int rp = wave >> 1, np = wave & 1;
  const int ntB = (OMODE == 5) ? blockIdx.y*4 : 0;
  f32x4 acc[STREAMS][2][2];
  #pragma unroll
  for (int s = 0; s < STREAMS; ++s)
    #pragma unroll
    for (int r = 0; r < 2; ++r)
      #pragma unroll
      for (int n = 0; n < 2; ++n) acc[s][r][n] = (f32x4){0.f,0.f,0.f,0.f};

  #pragma unroll 1
  for (int kc = 0; kc < KC; ++kc){
    if (kc) __syncthreads();
    for (int u = tid; u < STREAMS*216; u += 256){
      int st = u/216, r2 = u%216, p = r2>>1, h = r2&1;
      int rr = p/18, cc = p%18;
      size_t ga = (size_t)img*aImgStride + ((size_t)(y0+rr)*pitchIn + xs+cc)*csIn + kc*32 + h*16;
      const u16t* gp = ((STREAMS==2 && st==1) ? A1 : A0) + ga;
      short8 v0 = *(const short8*)gp;
      short8 v1 = *(const short8*)(gp + 8);
      u16t* lp = &sA[((size_t)(st*108 + p))*40 + h*16];
      *(short8*)lp = v0;
      *(short8*)(lp+8) = v1;
    }
    __syncthreads();
    #pragma unroll
    for (int tap = 0; tap < 9; ++tap){
      const int dy = tap/3, dx = tap%3;
      short8 af[STREAMS][2];
      #pragma unroll
      for (int st = 0; st < STREAMS; ++st)
        #pragma unroll
        for (int r = 0; r < 2; ++r)
          af[st][r] = *(const short8*)&sA[((size_t)(st*108 + (2*rp + r + dy)*18 + dx + m))*40 + q*8];
      const u16t* bp = Bp + ((size_t)(tap*KCtot + kc)*NTT + ntB + np*2)*512 + lane*8;
      short8 b0 = *(const short8*)bp;
      short8 b1 = *(const short8*)(bp + 512);
      #pragma unroll
      for (int st = 0; st < STREAMS; ++st)
        #pragma unroll
        for (int r = 0; r < 2; ++r){
          acc[st][r][0] = __builtin_amdgcn_mfma_f32_16x16x32_bf16(af[st][r], b0, acc[st][r][0], 0, 0, 0);
          acc[st][r][1] = __builtin_amdgcn_mfma_f32_16x16x32_bf16(af[st][r], b1, acc[st][r][1], 0, 0, 0);
        }
    }
  }
  const int px0 = q*4;
  #pragma unroll
  for (int r = 0; r < 2; ++r){
    int yout = y0 + 2*rp + r;
    #pragma unroll
    for (int n = 0; n < 2; ++n){
      int oL = (np*2 + n)*16 + m;
      if (OMODE == 4){
        float bv = bias[oL];
        #pragma unroll
        for (int g = 0; g < 4; ++g){
          int px = xs + px0 + g;
          float v = 0.1f*lrelu(acc[0][r][n][g] + bv) + lrelu(acc[1][r][n][g] + bv);
          outb[((size_t)(yout+1)*PDIM + px+1)*64 + oL] = f2b(v);
        }
      } else {
        int o = ntB*16 + oL;
        if (o < Cout){
          float bv = bias[o];
          #pragma unroll
          for (int g = 0; g < 4; ++g){
            int px = xs + px0 + g;
            outf[(size_t)o*HWF + (size_t)yout*IMW + px] = acc[0][r][n][g] + bv;
          }
        }
      }
    }
  }
}

// ---------- no-LDS MFMA implicit-GEMM (U-Net smalls); blockIdx.y = o-group of NT ----------
template<int NT, int KC, int STRIDE, int OMODE, int ACT, int SWZ>
__global__ __launch_bounds__(256) void gconv3(
    const u16t* __restrict__ A0, const u16t* __restrict__ Bp, const float* __restrict__ bias,
    float* __restrict__ outf, u16t* __restrict__ outb,
    int Cout, int Wout, int strips, int blocksPerImg,
    int pitchIn, int csIn, int coIn, size_t aImgStride,
    size_t outImgStride, int pitchOut, int csOut, int coOut,
    int KCtot, int NTtot)
{
  int bid = blockIdx.x;
  if (SWZ) bid = (bid & 7)*(gridDim.x >> 3) + (bid >> 3);
  const int wave = threadIdx.x >> 6;
  const int lane = threadIdx.x & 63;
  const int img = bid / blocksPerImg;
  const int sid = (bid - img*blocksPerImg)*4 + wave;
  const int y = sid / strips, xs = (sid % strips) * 16;
  const int m = lane & 15, q = lane >> 4;
  const int ntOff = blockIdx.y*NT;
  f32x4 acc[NT];
  #pragma unroll
  for (int nt = 0; nt < NT; ++nt) acc[nt] = (f32x4){0.f,0.f,0.f,0.f};

  for (int tap = 0; tap < 9; ++tap){
    int dy = tap/3, dx = tap%3;
    int row = STRIDE*y + dy;
    int col = (STRIDE == 1) ? (xs + m + dx) : (2*(xs + m) + dx);
    size_t abase = (size_t)img*aImgStride + ((size_t)row*pitchIn + col)*csIn + coIn + q*8;
    const u16t* ap0 = A0 + abase;
    const u16t* bp = Bp + ((size_t)(tap*KCtot)*NTtot + ntOff)*512 + lane*8;
    #pragma unroll
    for (int kc = 0; kc < KC; ++kc){
      short8 av0 = *(const short8*)(ap0 + kc*32);
      #pragma unroll
      for (int nt = 0; nt < NT; ++nt){
        short8 bv = *(const short8*)(bp + (size_t)(kc*NTtot + nt)*512);
        acc[nt] = __builtin_amdgcn_mfma_f32_16x16x32_bf16(av0, bv, acc[nt], 0, 0, 0);
      }
    }
  }
  const int prow0 = q*4;
  #pragma unroll
  for (int nt = 0; nt < NT; ++nt){
    int o = (ntOff + nt)*16 + m;
    if (o >= Cout) continue;
    float bv = bias[o];
    #pragma unroll
    for (int r = 0; r < 4; ++r){
      int px = xs + prow0 + r;
      if (px >= Wout) continue;
      float v = acc[nt][r] + bv;
      if (ACT) v = fmaxf(v, 0.f);
      if (OMODE == 0){
        outf[((size_t)img*Cout + o)*((size_t)Wout*Wout) + (size_t)y*Wout + px] = v;
      } else if (OMODE == 1){
        outb[(size_t)img*outImgStride + ((size_t)(y+1)*pitchOut + px+1)*csOut + coOut + o] = f2b(v);
      } else {
        outb[(size_t)img*outImgStride + ((size_t)y*pitchOut + px)*csOut + coOut + o] = f2b(v);
      }
    }
  }
}

// ---------- gating + flow-warp, channels-last bf16, XCD-banded, all 7 t per thread ----------
// grid 144: xcd = bid&7 owns a 24-row band; ref slice read ONCE per pixel.
__global__ __launch_bounds__(256) void gate_nhwc(
    const u16t* __restrict__ fpad, const u16t* __restrict__ pred,
    const float* __restrict__ mv, u16t* __restrict__ spad)
{
  int bid = blockIdx.x;
  int xcd = bid & 7, lb = bid >> 3;
  int idx = (xcd*18 + lb)*256 + threadIdx.x;
  int y = idx/IMW, x = idx%IMW;
  size_t pc = ((size_t)(y+1)*PDIM + (x+1))*448;
  const u16t* rp = fpad + pc + 192;
  short8 r8[8];
  #pragma unroll
  for (int c8 = 0; c8 < 8; ++c8) r8[c8] = *(const short8*)(rp + c8*8);
  #pragma unroll 1
  for (int t = 0; t < 7; ++t){
    const u16t* pp = pred + ((size_t)t*HWF + idx)*64;
    u16t* sp = spad + pc + (size_t)t*64;
    const u16t* tp[4]; float tw[4];
    if (t == 0){
      tp[0] = fpad + pc; tw[0] = 1.f;
      tp[1] = tp[2] = tp[3] = fpad + pc; tw[1] = tw[2] = tw[3] = 0.f;
    } else {
      float fx = mv[(((size_t)(t-1)*HWF + idx))*2 + 0];
      float fy = mv[(((size_t)(t-1)*HWF + idx))*2 + 1];
      float ys = (float)y + fy, xsf = (float)x + fx;
      float y0f = floorf(ys), x0f = floorf(xsf);
      float wy = ys - y0f, wx = xsf - x0f;
      int y0 = (int)y0f, x0i = (int)x0f;
      int kk = 0;
      #pragma unroll
      for (int dy2 = 0; dy2 < 2; ++dy2)
        #pragma unroll
        for (int dx2 = 0; dx2 < 2; ++dx2){
          int yi = y0+dy2, xi = x0i+dx2;
          float wv = (dy2 ? wy : 1.f-wy)*(dx2 ? wx : 1.f-wx);
          bool ok = (yi >= 0 && yi <= 191 && xi >= 0 && xi <= 191);
          int yc = min(max(yi,0),191), xc = min(max(xi,0),191);
          tp[kk] = fpad + ((size_t)(yc+1)*PDIM + xc+1)*448 + (size_t)(t-1)*64;
          tw[kk] = ok ? wv : 0.f;
          ++kk;
        }
    }
    #pragma unroll
    for (int c8 = 0; c8 < 8; ++c8){
      short8 pv = *(const short8*)(pp + c8*8);
      short8 t0v = *(const short8*)(tp[0] + c8*8);
      short8 t1v = *(const short8*)(tp[1] + c8*8);
      short8 t2v = *(const short8*)(tp[2] + c8*8);
      short8 t3v = *(const short8*)(tp[3] + c8*8);
      short8 ov;
      #pragma unroll
      for (int j = 0; j < 8; ++j){
        float r = b2f((u16t)r8[c8][j]);
        float p = b2f((u16t)pv[j]);
        float a = tw[0]*b2f((u16t)t0v[j]) + tw[1]*b2f((u16t)t1v[j])
                + tw[2]*b2f((u16t)t2v[j]) + tw[3]*b2f((u16t)t3v[j]);
        float sv = a*sigmoidf(a*r) + p*sigmoidf(p*r);
        ov[j] = (short)f2b(sv);
      }
      *(short8*)(sp + c8*8) = ov;
    }
  }
}

// ---------------- convT 4x4 s2 p1 (+relu): parity-decomposed, fp32 in, bf16 NHWC out ----------------
__global__ __launch_bounds__(256) void convT_tile2(
    const float* __restrict__ in, const float* __restrict__ wp,
    const float* __restrict__ bias, u16t* __restrict__ outb,
    int Hin, int tilesX, int pitchOut, int csOut, int coOut)
{
  const int CC = 4;
  __shared__ float sIn[CC][10*11];
  __shared__ float sW[16][CC][4][4];
  const int Win = Hin;
  const int o0 = blockIdx.x*16;
  const int tile = blockIdx.y;
  const int ty0 = (tile/tilesX)*16, tx0 = (tile%tilesX)*16;
  const int tid = threadIdx.x;
  const int py = tid>>4, px = tid&15;
  const int ry = py&1, rx = px&1, par = ry*2 + rx;
  const int lr = py>>1, lc = px>>1;
  const int r0 = ty0>>1, c0 = tx0>>1;
  float acc[16] = {};
  for (int ib = 0; ib < 64; ib += CC){
    for (int i = tid; i < CC*100; i += 256){
      int c = i/100, rem = i%100, r = rem/10, col = rem%10;
      int gy = r0 - 1 + r, gx = c0 - 1 + col;
      float v = 0.f;
      if (gy >= 0 && gy < Hin && gx >= 0 && gx < Win)
        v = in[(size_t)(ib + c)*Hin*Win + gy*Win + gx];
      sIn[c][r*11 + col] = v;
    }
    for (int i = tid; i < 1024; i += 256){
      int ol = i >> 6, rem = i & 63, ci = rem >> 4, p2 = (rem >> 2) & 3, j = rem & 3;
      sW[ol][ci][p2][j] = wp[((size_t)((p2*64 + o0 + ol)*64) + ib + ci)*4 + j];
    }
    __syncthreads();
    #pragma unroll
    for (int ci = 0; ci < CC; ++ci){
      int rb = lr + ry, cb = lc + rx;
      float t00 = sIn[ci][rb*11 + cb],     t01 = sIn[ci][rb*11 + cb + 1];
      float t10 = sIn[ci][(rb+1)*11 + cb], t11 = sIn[ci][(rb+1)*11 + cb + 1];
      #pragma unroll
      for (int ol = 0; ol < 16; ++ol){
        const float* wv = &sW[ol][ci][par][0];
        acc[ol] += t00*wv[0] + t01*wv[1] + t10*wv[2] + t11*wv[3];
      }
    }
    __syncthreads();
  }
  int gy = ty0 + py, gx = tx0 + px;
  u16t* op = outb + ((size_t)(gy+1)*pitchOut + gx+1)*csOut + coOut + o0;
  short8 pa, pb;
  #pragma unroll
  for (int i = 0; i < 8; ++i) pa[i] = (short)f2b(fmaxf(acc[i] + bias[o0+i], 0.f));
  #pragma unroll
  for (int i = 0; i < 8; ++i) pb[i] = (short)f2b(fmaxf(acc[8+i] + bias[o0+8+i], 0.f));
  *(short8*)op = pa;
  *(short8*)(op + 8) = pb;
}

// ---------------- deformable conv ----------------
__global__ __launch_bounds__(256) void deform_sample_k(
    const float* __restrict__ lqs, const float* __restrict__ om,
    float* __restrict__ vbuf)
{
  int idx = blockIdx.x*256 + threadIdx.x;
  int g = blockIdx.y;
  int h = idx / IMW, x = idx % IMW;
  const float* img = lqs + (size_t)g*HWF;
  #pragma unroll
  for (int k = 0; k < 9; ++k){
    int j = g*9 + k;
    float offy = om[(size_t)(j*2 + 0)*HWF + idx];
    float offx = om[(size_t)(j*2 + 1)*HWF + idx];
    float m = sigmoidf(om[(size_t)(126 + j)*HWF + idx]);
    float ys = (float)(h + (k/3) - 1) + offy;
    float xs = (float)(x + (k%3) - 1) + offx;
    vbuf[(size_t)j*HWF + idx] = bilin(img, ys, xs, IMH, IMW) * m;
  }
}

__global__ __launch_bounds__(256) void deform_out_k(
    const float* __restrict__ vbuf, const float* __restrict__ dcw,
    const float* __restrict__ dcb, float* __restrict__ out)
{
  __shared__ float sw[16*63];
  int idx = blockIdx.x*256 + threadIdx.x;
  int o0 = blockIdx.y*16;
  for (int i = threadIdx.x; i < 16*63; i += 256)
    sw[i] = dcw[(size_t)o0*63 + i];
  __syncthreads();
  float v[63];
  #pragma unroll
  for (int j = 0; j < 63; ++j) v[j] = vbuf[(size_t)j*HWF + idx];
  for (int ol = 0; ol < 16; ++ol){
    float acc = dcb[o0 + ol];
    #pragma unroll
    for (int j = 0; j < 63; ++j) acc += v[j]*sw[ol*63 + j];
    out[(size_t)(o0 + ol)*HWF + idx] = fmaxf(acc, 0.f);
  }
}

extern "C" void kernel_launch(void* const* d_in, const int* in_sizes, int n_in,
                              void* d_out, int out_size, void* d_ws, size_t ws_size,
                              hipStream_t stream)
{
  const float* lqs   = (const float*)d_in[0];
  const float* preds = (const float*)d_in[1];
  const float* mv    = (const float*)d_in[2];
  const float* bw1   = (const float*)d_in[3];
  const float* bb1   = (const float*)d_in[4];
  const float* bw2   = (const float*)d_in[5];
  const float* bb2   = (const float*)d_in[6];
  const float* dn1w  = (const float*)d_in[7];
  const float* dn1b  = (const float*)d_in[8];
  const float* dn2w  = (const float*)d_in[9];
  const float* dn2b  = (const float*)d_in[10];
  const float* up1cw = (const float*)d_in[11];
  const float* up1cb = (const float*)d_in[12];
  const float* up1tw = (const float*)d_in[13];
  const float* up1tb = (const float*)d_in[14];
  const float* up2cw = (const float*)d_in[15];
  const float* up2cb = (const float*)d_in[16];
  const float* up2tw = (const float*)d_in[17];
  const float* up2tb = (const float*)d_in[18];
  const float* trcw  = (const float*)d_in[19];
  const float* trcb  = (const float*)d_in[20];
  const float* trtw  = (const float*)d_in[21];
  const float* trtb  = (const float*)d_in[22];
  const float* ffw   = (const float*)d_in[23];
  const float* ffb   = (const float*)d_in[24];
  const float* omw   = (const float*)d_in[25];
  const float* omb   = (const float*)d_in[26];
  const float* dcw   = (const float*)d_in[27];
  const float* dcb   = (const float*)d_in[28];
  float* outp = (float*)d_out;

  char* p = (char*)d_ws;
  const size_t PIMG64 = (size_t)PDIM*PDIM*64;
  u16t* spadreg  = (u16t*)p; p += 14*PIMG64*2;                // spad [194][194][448]; later featfpad
  u16t* fpad     = (u16t*)p; p += (size_t)PDIM*PDIM*448*2;    // feat NHWC448; later vbuf (fp32)
  u16t* prednhwc = (u16t*)p; p += (size_t)7*HWF*64*2;         // pred NHWC64; later om (fp32)
  u16t* out0pad  = (u16t*)p; p += (size_t)PDIM*PDIM*64*2;
  u16t* cat1pad  = (u16t*)p; p += (size_t)98*98*128*2;
  u16t* cat2pad  = (u16t*)p; p += (size_t)50*50*128*2;
  float* t0      = (float*)p; p += (size_t)24*24*64*4;
  float* u2      = (float*)p; p += (size_t)48*48*64*4;
  float* u1      = (float*)p; p += (size_t)96*96*64*4;
  u16t* ffwpack  = (u16t*)p; p += 258048*2;
  u16t* c2pack   = (u16t*)p; p += 36864*2;
  u16t* ompack   = (u16t*)p; p += 110592*2;
  u16t* dn1pack  = (u16t*)p; p += 36864*2;
  u16t* dn2pack  = (u16t*)p; p += 36864*2;
  u16t* trcpack  = (u16t*)p; p += 36864*2;
  u16t* up2cpack = (u16t*)p; p += 73728*2;
  u16t* up1cpack = (u16t*)p; p += 73728*2;
  float* wp0     = (float*)p; p += 65536*4;
  float* wp1     = (float*)p; p += 65536*4;
  float* wp2     = (float*)p; p += 65536*4;

  u16t* spad = spadreg;
  u16t* featfpad = spadreg;
  float* om = (float*)prednhwc;
  float* vbuf = (float*)fpad;

  dim3 blk(256);
  // setup
  PkD8 pk = {{ {ffw, ffwpack, 448, 64, 4, 258048}, {bw2, c2pack, 64, 64, 4, 36864},
               {omw, ompack, 64, 189, 12, 110592}, {dn1w, dn1pack, 64, 64, 4, 36864},
               {dn2w, dn2pack, 64, 64, 4, 36864},  {trcw, trcpack, 64, 64, 4, 36864},
               {up2cw, up2cpack, 128, 64, 4, 73728}, {up1cw, up1cpack, 128, 64, 4, 73728} }};
  pack_all<<<dim3(1008,8), blk, 0, stream>>>(pk);
  RpD3 rp3 = {{ {trtw, wp0}, {up2tw, wp1}, {up1tw, wp2} }};
  repack_all<<<dim3(64,3), blk, 0, stream>>>(rp3);
  PzD5 pz = {{ {spad, 448, PDIM, 1, 0}, {fpad, 448, PDIM, 1, 0},
               {out0pad, 64, PDIM, 1, 0}, {cat1pad, 128, 98, 1, 0}, {cat2pad, 128, 50, 1, 0} }};
  padzero_all<<<dim3(2704,5), blk, 0, stream>>>(pz);
  // fused backbone (conv1+conv2, no HBM intermediate)
  bbfused<<<dim3(8064), blk, 0, stream>>>(lqs, preds, bw1, bb1, c2pack, bb2, fpad, prednhwc);
  // gate (+warp) -> spad (XCD-banded, all-t per thread)
  gate_nhwc<<<dim3(144), blk, 0, stream>>>(fpad, prednhwc, mv, spad);
  // fused dual conv -> out0pad
  cgemm<2,14,4,4,1><<<dim3(576,1), blk, 0, stream>>>(spad, fpad, ffwpack, ffb,
      nullptr, out0pad, nullptr, 64, 576, PDIM, 448, 0, 14);
  // U-Net (NT=1 o-splits for occupancy)
  gconv3<1,2,2,1,1,1><<<dim3(144,4), blk, 0, stream>>>(out0pad, dn1pack, dn1b, nullptr, cat1pad,
      64, 96, 6, 144, PDIM, 64, 0, 0, 0, 98, 128, 64, 2, 4);       // out1 -> cat1[64:]
  gconv3<1,2,2,1,1,0><<<dim3(36,4), blk, 0, stream>>>(cat1pad, dn2pack, dn2b, nullptr, cat2pad,
      64, 48, 3, 36, 98, 128, 64, 0, 0, 50, 128, 64, 2, 4);        // out2 -> cat2[64:]
  gconv3<1,2,2,0,1,0><<<dim3(12,4), blk, 0, stream>>>(cat2pad, trcpack, trcb, t0, nullptr,
      64, 24, 2, 12, 50, 128, 64, 0, 0, 0, 0, 0, 2, 4);            // t0 (fp32 NCHW)
  convT_tile2<<<dim3(4,9), blk, 0, stream>>>(t0, wp0, trtb, cat2pad, 24, 3, 50, 128, 0);   // t1 -> cat2[:64]
  gconv3<1,4,1,0,1,0><<<dim3(36,4), blk, 0, stream>>>(cat2pad, up2cpack, up2cb, u2, nullptr,
      64, 48, 3, 36, 50, 128, 0, 0, 0, 0, 0, 0, 4, 4);             // u2 (fp32 NCHW)
  convT_tile2<<<dim3(4,36), blk, 0, stream>>>(u2, wp1, up2tb, cat1pad, 48, 6, 98, 128, 0); // u2t -> cat1[:64]
  gconv3<1,4,1,0,1,1><<<dim3(144,4), blk, 0, stream>>>(cat1pad, up1cpack, up1cb, u1, nullptr,
      64, 96, 6, 144, 98, 128, 0, 0, 0, 0, 0, 0, 4, 4);            // u1 (fp32 NCHW)
  // final convT -> featfpad (region free after fuse consumed spad)
  padzero2<<<dim3(194), blk, 0, stream>>>(featfpad, 64, PDIM);
  convT_tile2<<<dim3(4,144), blk, 0, stream>>>(u1, wp2, up1tb, featfpad, 96, 12, PDIM, 64, 0);
  // offsets/masks conv (64 -> 189)
  cgemm<1,2,5,12,1><<<dim3(576,3), blk, 0, stream>>>(featfpad, nullptr, ompack, omb,
      om, nullptr, nullptr, 189, 576, PDIM, 64, 0, 2);
  // deformable conv
  deform_sample_k<<<dim3(144,7), blk, 0, stream>>>(lqs, om, vbuf);
  deform_out_k<<<dim3(144,4), blk, 0, stream>>>(vbuf, dcw, dcb, outp);
}